// Round 1
// baseline (1641.657 us; speedup 1.0000x reference)
//
#include <hip/hip_runtime.h>
#include <math.h>

#define CC    768
#define C3    2304
#define TT    1024
#define BB    4
#define HH    12
#define HD    64
#define EE    16
#define DFFN  3072
#define NTOK  4096
#define NROW  49152   /* B*H*T */
#define NSLOT 8192    /* NTOK * top-2 */

typedef unsigned short u16;
typedef unsigned int   u32;
typedef __attribute__((ext_vector_type(8))) short short8;
typedef __attribute__((ext_vector_type(4))) float floatx4;

__device__ __forceinline__ u16 f2bf(float f){
  u32 x = __builtin_bit_cast(u32, f);
  x += 0x7fffu + ((x >> 16) & 1u);   // RNE
  return (u16)(x >> 16);
}
__device__ __forceinline__ float bf2f(u16 u){
  return __builtin_bit_cast(float, (u32)u << 16);
}
__device__ __forceinline__ void split3(float v, u16* a, u16* b, u16* c, size_t i){
  u16 h0 = f2bf(v); a[i] = h0;
  float r = v - bf2f(h0);
  u16 h1 = f2bf(r); b[i] = h1;
  c[i] = f2bf(r - bf2f(h1));
}
__device__ __forceinline__ float gelu_exact(float v){
  return 0.5f * v * (1.f + erff(v * 0.70710678118654752440f));
}

// ---------------- fp32 -> bf16 transpose (+optional 3-way split) ----------------
// src [z][R][Cn] fp32 -> dst [z][Cn][R] bf16
template<int NS>
__global__ __launch_bounds__(256) void transpose_split(const float* __restrict__ src,
    u16* __restrict__ d0, u16* __restrict__ d1, u16* __restrict__ d2, int R, int Cn)
{
  __shared__ float tile[32][33];
  int z = blockIdx.z;
  const float* s = src + (size_t)z * R * Cn;
  size_t dbase = (size_t)z * R * Cn;
  int c0 = blockIdx.x * 32, r0 = blockIdx.y * 32;
  int tx = threadIdx.x & 31, ty = threadIdx.x >> 5;
  #pragma unroll
  for (int j = 0; j < 4; ++j)
    tile[ty + j*8][tx] = s[(size_t)(r0 + ty + j*8) * Cn + c0 + tx];
  __syncthreads();
  #pragma unroll
  for (int j = 0; j < 4; ++j){
    float v = tile[tx][ty + j*8];
    size_t di = dbase + (size_t)(c0 + ty + j*8) * R + r0 + tx;
    if (NS == 3) split3(v, d0, d1, d2, di);
    else d0[di] = f2bf(v);
  }
}

// ---------------- LayerNorm (optionally fp32 out, single-bf16 out, or 3-split out) --
__global__ __launch_bounds__(256) void ln_kernel(const float* __restrict__ x,
    const float* __restrict__ gw, const float* __restrict__ gb,
    float* __restrict__ of, u16* __restrict__ o0, u16* __restrict__ o1, u16* __restrict__ o2)
{
  int tok = blockIdx.x, tid = threadIdx.x;
  const float* xr = x + (size_t)tok * CC;
  float v0 = xr[tid], v1 = xr[tid + 256], v2 = xr[tid + 512];
  __shared__ float r1[4], r2[4];
  __shared__ float mus, rss;
  float s = v0 + v1 + v2;
  #pragma unroll
  for (int off = 32; off >= 1; off >>= 1) s += __shfl_down(s, off);
  if ((tid & 63) == 0) r1[tid >> 6] = s;
  __syncthreads();
  if (tid == 0) mus = (r1[0] + r1[1] + r1[2] + r1[3]) * (1.f / 768.f);
  __syncthreads();
  float mu = mus;
  float d0 = v0 - mu, d1 = v1 - mu, d2 = v2 - mu;
  float t = d0*d0 + d1*d1 + d2*d2;
  #pragma unroll
  for (int off = 32; off >= 1; off >>= 1) t += __shfl_down(t, off);
  if ((tid & 63) == 0) r2[tid >> 6] = t;
  __syncthreads();
  if (tid == 0) rss = rsqrtf((r2[0] + r2[1] + r2[2] + r2[3]) * (1.f / 768.f) + 1e-5f);
  __syncthreads();
  float rstd = rss;
  float dv[3] = {d0, d1, d2};
  #pragma unroll
  for (int i = 0; i < 3; ++i){
    int c = tid + i * 256;
    float vv = dv[i] * rstd * gw[c] + gb[c];
    size_t idx = (size_t)tok * CC + c;
    if (of) of[idx] = vv;
    if (o1) split3(vv, o0, o1, o2, idx);
    else if (o0) o0[idx] = f2bf(vv);
  }
}

// ---------------- dense bf16 NT GEMM: C[M][N] (+)= A[M][K] * Bt[N][K]^T + bias ------
template<int BETA>
__global__ __launch_bounds__(256) void gemm_dense(
    const u16* __restrict__ A, const u16* __restrict__ Bt,
    float* __restrict__ C, const float* __restrict__ bias,
    int M, int N, int K)
{
  __shared__ u16 As[128 * 32];
  __shared__ u16 Bs[128 * 32];
  int tid = threadIdx.x;
  int lane = tid & 63, wave = tid >> 6;
  int wm = wave & 1, wn = wave >> 1;
  int m0 = blockIdx.y * 128, n0 = blockIdx.x * 128;
  int ra = tid >> 2, ka = (tid & 3) * 8;
  const u16* pa0 = A  + (size_t)(m0 + ra)      * K + ka;
  const u16* pa1 = A  + (size_t)(m0 + ra + 64) * K + ka;
  const u16* pb0 = Bt + (size_t)(n0 + ra)      * K + ka;
  const u16* pb1 = Bt + (size_t)(n0 + ra + 64) * K + ka;
  floatx4 acc[4][4] = {};
  int el = lane & 15, eq = lane >> 4;
  for (int k0 = 0; k0 < K; k0 += 32){
    __syncthreads();
    uint4 va0 = *(const uint4*)(pa0 + k0);
    uint4 va1 = *(const uint4*)(pa1 + k0);
    uint4 vb0 = *(const uint4*)(pb0 + k0);
    uint4 vb1 = *(const uint4*)(pb1 + k0);
    *(uint4*)&As[(size_t)ra * 32 + ka]        = va0;
    *(uint4*)&As[(size_t)(ra + 64) * 32 + ka] = va1;
    *(uint4*)&Bs[(size_t)ra * 32 + ka]        = vb0;
    *(uint4*)&Bs[(size_t)(ra + 64) * 32 + ka] = vb1;
    __syncthreads();
    short8 fa[4], fb[4];
    #pragma unroll
    for (int t = 0; t < 4; ++t)
      fa[t] = *(const short8*)&As[(size_t)(wm*64 + t*16 + el) * 32 + eq*8];
    #pragma unroll
    for (int t = 0; t < 4; ++t)
      fb[t] = *(const short8*)&Bs[(size_t)(wn*64 + t*16 + el) * 32 + eq*8];
    #pragma unroll
    for (int mt = 0; mt < 4; ++mt)
      #pragma unroll
      for (int nt = 0; nt < 4; ++nt)
        acc[mt][nt] = __builtin_amdgcn_mfma_f32_16x16x32_bf16(fa[mt], fb[nt], acc[mt][nt], 0, 0, 0);
  }
  #pragma unroll
  for (int mt = 0; mt < 4; ++mt){
    #pragma unroll
    for (int nt = 0; nt < 4; ++nt){
      int col = n0 + wn*64 + nt*16 + el;
      float bv = bias ? bias[col] : 0.f;
      #pragma unroll
      for (int r = 0; r < 4; ++r){
        int row = m0 + wm*64 + mt*16 + eq*4 + r;
        size_t idx = (size_t)row * N + col;
        float val = acc[mt][nt][r] + bv;
        if (BETA) val += C[idx];
        C[idx] = val;
      }
    }
  }
}

// ---------------- fp32 flash attention, key-split partials ----------------
// grid (16 rowtiles, 4 splits, B*H), block 64. Partials: o (unnormalized), m, l.
__global__ __launch_bounds__(64) void flash1(const float* __restrict__ qkv,
    float* __restrict__ opart, float* __restrict__ mpart, float* __restrict__ lpart)
{
  __shared__ float Kl[32 * 64];
  __shared__ float Vl[32 * 64];
  int lane = threadIdx.x;
  int rowtile = blockIdx.x, split = blockIdx.y, bh = blockIdx.z;
  int b = bh / HH, h = bh % HH;
  int r = rowtile * 64 + lane;
  const float* qr = qkv + ((size_t)(b * TT + r)) * C3 + h * HD;
  floatx4 q[16], o[16];
  #pragma unroll
  for (int i = 0; i < 16; ++i){ q[i] = *(const floatx4*)(qr + i*4); o[i] = (floatx4){0.f,0.f,0.f,0.f}; }
  float m = -1e30f, l = 0.f;
  int last = rowtile * 2 + 1;
  for (int kt = split; kt <= last; kt += 4){
    __syncthreads();
    #pragma unroll
    for (int i = 0; i < 8; ++i){
      int c = i * 64 + lane;
      int j = c >> 4, ch = c & 15;
      size_t base = ((size_t)(b * TT + kt*32 + j)) * C3 + h * HD + ch * 4;
      *(floatx4*)&Kl[j*64 + ch*4] = *(const floatx4*)(qkv + base + CC);
      *(floatx4*)&Vl[j*64 + ch*4] = *(const floatx4*)(qkv + base + 2*CC);
    }
    __syncthreads();
    int jmax = r - kt * 32;
    if (jmax >= 0){
      if (jmax > 31) jmax = 31;
      for (int j = 0; j <= jmax; ++j){
        const floatx4* kr = (const floatx4*)&Kl[j*64];
        float s = 0.f;
        #pragma unroll
        for (int i = 0; i < 16; ++i){
          floatx4 k4 = kr[i];
          s += q[i].x*k4.x + q[i].y*k4.y + q[i].z*k4.z + q[i].w*k4.w;
        }
        s *= 0.125f;
        const floatx4* vr = (const floatx4*)&Vl[j*64];
        if (s <= m){
          float p = expf(s - m);
          l += p;
          #pragma unroll
          for (int i = 0; i < 16; ++i){
            floatx4 v4 = vr[i];
            o[i].x += p*v4.x; o[i].y += p*v4.y; o[i].z += p*v4.z; o[i].w += p*v4.w;
          }
        } else {
          float al = expf(m - s);       // new max: p = 1
          m = s; l = l * al + 1.f;
          #pragma unroll
          for (int i = 0; i < 16; ++i){
            floatx4 v4 = vr[i];
            o[i].x = o[i].x*al + v4.x; o[i].y = o[i].y*al + v4.y;
            o[i].z = o[i].z*al + v4.z; o[i].w = o[i].w*al + v4.w;
          }
        }
      }
    }
  }
  size_t idx = (size_t)split * NROW + (size_t)bh * TT + r;
  mpart[idx] = m; lpart[idx] = l;
  float* op = opart + idx * 64;
  #pragma unroll
  for (int i = 0; i < 16; ++i) *(floatx4*)(op + i*4) = o[i];
}

// merge 4 key-split partials -> y, written as 3-way bf16 split [tok][C]
__global__ __launch_bounds__(256) void flash2(const float* __restrict__ opart,
    const float* __restrict__ mpart, const float* __restrict__ lpart,
    u16* __restrict__ y0, u16* __restrict__ y1, u16* __restrict__ y2)
{
  int gid = blockIdx.x * 256 + threadIdx.x;
  int row = gid >> 6, d = gid & 63;
  float m0 = mpart[row],          m1 = mpart[NROW + row];
  float m2 = mpart[2*NROW + row], m3 = mpart[3*NROW + row];
  float M = fmaxf(fmaxf(m0, m1), fmaxf(m2, m3));
  float e0 = expf(m0 - M), e1 = expf(m1 - M), e2 = expf(m2 - M), e3 = expf(m3 - M);
  float den = lpart[row]*e0 + lpart[NROW+row]*e1 + lpart[2*NROW+row]*e2 + lpart[3*NROW+row]*e3;
  float num = opart[(size_t)row*64 + d]            * e0
            + opart[(size_t)(NROW   + row)*64 + d] * e1
            + opart[(size_t)(2*NROW + row)*64 + d] * e2
            + opart[(size_t)(3*NROW + row)*64 + d] * e3;
  float y = num / den;
  int bh = row >> 10, t = row & 1023;
  int b = bh / HH, h = bh % HH;
  size_t di = (size_t)(b * TT + t) * CC + h * HD + d;
  split3(y, y0, y1, y2, di);
}

// ---------------- router: fp32 logits, softmax, top-2 ----------------
__global__ __launch_bounds__(256) void router_kernel(const float* __restrict__ xn2,
    const float* __restrict__ Wr, int* __restrict__ eids, float* __restrict__ wts)
{
  int wave = threadIdx.x >> 6, lane = threadIdx.x & 63;
  int tok = blockIdx.x * 4 + wave;
  int g = lane >> 4, e = lane & 15;
  const float* xr = xn2 + (size_t)tok * CC;
  float s = 0.f;
  for (int c4 = 0; c4 < 192; ++c4){
    int c = c4 * 4 + g;
    s += xr[c] * Wr[c * EE + e];
  }
  s += __shfl_xor(s, 16);
  s += __shfl_xor(s, 32);              // every lane: logit for expert (lane&15)
  float mx = s;
  #pragma unroll
  for (int off = 1; off < 16; off <<= 1) mx = fmaxf(mx, __shfl_xor(mx, off));
  float p = expf(s - mx);
  float Z = p;
  #pragma unroll
  for (int off = 1; off < 16; off <<= 1) Z += __shfl_xor(Z, off);
  p /= Z;
  float best = -1.f; int bi = 0;
  for (int ee = 0; ee < 16; ++ee){
    float pe = __shfl(p, ee);
    if (pe > best){ best = pe; bi = ee; }
  }
  float sec = -1.f; int si = 0;
  for (int ee = 0; ee < 16; ++ee){
    float pe = __shfl(p, ee);
    if (ee != bi && pe > sec){ sec = pe; si = ee; }
  }
  if (lane == 0){
    eids[tok*2] = bi;  eids[tok*2+1] = si;
    wts [tok*2] = best; wts[tok*2+1] = sec;
  }
}

__global__ __launch_bounds__(256) void moe_count(const int* __restrict__ eids,
    int* __restrict__ counts, int* __restrict__ offs, int* __restrict__ curs)
{
  __shared__ int lc[EE];
  int tid = threadIdx.x;
  if (tid < EE) lc[tid] = 0;
  __syncthreads();
  for (int i = tid; i < NSLOT; i += 256) atomicAdd(&lc[eids[i]], 1);
  __syncthreads();
  if (tid == 0){
    int run = 0;
    for (int e = 0; e < EE; ++e){
      counts[e] = lc[e]; offs[e] = run; curs[e] = run; run += lc[e];
    }
    offs[EE] = run;
  }
}

__global__ __launch_bounds__(256) void moe_scatter(const int* __restrict__ eids,
    const float* __restrict__ wts, int* __restrict__ curs,
    int* __restrict__ rowmap, float* __restrict__ wgtm)
{
  int i = blockIdx.x * 256 + threadIdx.x;
  int e = eids[i];
  int pos = atomicAdd(&curs[e], 1);
  rowmap[pos] = i >> 1;
  wgtm[pos] = wts[i];
}

__global__ __launch_bounds__(256) void add2(const float* __restrict__ a,
    const float* __restrict__ b, float* __restrict__ o, int n)
{
  int i = blockIdx.x * 256 + threadIdx.x;
  if (i < n) o[i] = a[i] + b[i];
}

// ---------------- MoE expert GEMM1: H = gelu(gather(xn2b) @ W1t^T + b1) ----------------
__global__ __launch_bounds__(256) void gemm_moe1(
    const u16* __restrict__ Xb, const u16* __restrict__ W1t, const float* __restrict__ b1,
    u16* __restrict__ H, const int* __restrict__ counts, const int* __restrict__ offs,
    const int* __restrict__ rowmap)
{
  int e = blockIdx.z;
  int cnt = counts[e];
  int m0 = blockIdx.y * 128;
  if (m0 >= cnt) return;
  int off = offs[e];
  int n0 = blockIdx.x * 128;
  const u16* Bt = W1t + (size_t)e * DFFN * CC;
  __shared__ u16 As[128 * 32];
  __shared__ u16 Bs[128 * 32];
  int tid = threadIdx.x;
  int lane = tid & 63, wave = tid >> 6;
  int wm = wave & 1, wn = wave >> 1;
  int ra = tid >> 2, ka = (tid & 3) * 8;
  int r0 = m0 + ra, r1i = m0 + ra + 64;
  const u16* pa0 = (r0  < cnt) ? Xb + (size_t)rowmap[off + r0]  * CC + ka : nullptr;
  const u16* pa1 = (r1i < cnt) ? Xb + (size_t)rowmap[off + r1i] * CC + ka : nullptr;
  const u16* pb0 = Bt + (size_t)(n0 + ra)      * CC + ka;
  const u16* pb1 = Bt + (size_t)(n0 + ra + 64) * CC + ka;
  floatx4 acc[4][4] = {};
  int el = lane & 15, eq = lane >> 4;
  uint4 z4 = {0u, 0u, 0u, 0u};
  for (int k0 = 0; k0 < CC; k0 += 32){
    __syncthreads();
    uint4 va0 = pa0 ? *(const uint4*)(pa0 + k0) : z4;
    uint4 va1 = pa1 ? *(const uint4*)(pa1 + k0) : z4;
    uint4 vb0 = *(const uint4*)(pb0 + k0);
    uint4 vb1 = *(const uint4*)(pb1 + k0);
    *(uint4*)&As[(size_t)ra * 32 + ka]        = va0;
    *(uint4*)&As[(size_t)(ra + 64) * 32 + ka] = va1;
    *(uint4*)&Bs[(size_t)ra * 32 + ka]        = vb0;
    *(uint4*)&Bs[(size_t)(ra + 64) * 32 + ka] = vb1;
    __syncthreads();
    short8 fa[4], fb[4];
    #pragma unroll
    for (int t = 0; t < 4; ++t)
      fa[t] = *(const short8*)&As[(size_t)(wm*64 + t*16 + el) * 32 + eq*8];
    #pragma unroll
    for (int t = 0; t < 4; ++t)
      fb[t] = *(const short8*)&Bs[(size_t)(wn*64 + t*16 + el) * 32 + eq*8];
    #pragma unroll
    for (int mt = 0; mt < 4; ++mt)
      #pragma unroll
      for (int nt = 0; nt < 4; ++nt)
        acc[mt][nt] = __builtin_amdgcn_mfma_f32_16x16x32_bf16(fa[mt], fb[nt], acc[mt][nt], 0, 0, 0);
  }
  #pragma unroll
  for (int mt = 0; mt < 4; ++mt){
    #pragma unroll
    for (int nt = 0; nt < 4; ++nt){
      int col = n0 + wn*64 + nt*16 + el;
      float bv = b1[(size_t)e * DFFN + col];
      #pragma unroll
      for (int r = 0; r < 4; ++r){
        int row = m0 + wm*64 + mt*16 + eq*4 + r;
        if (row < cnt)
          H[(size_t)(off + row) * DFFN + col] = f2bf(gelu_exact(acc[mt][nt][r] + bv));
      }
    }
  }
}

// ---------------- MoE expert GEMM2: out[tok] += w * (H @ W2t^T + b2) ----------------
__global__ __launch_bounds__(256) void gemm_moe2(
    const u16* __restrict__ H, const u16* __restrict__ W2t, const float* __restrict__ b2,
    float* __restrict__ Out, const int* __restrict__ counts, const int* __restrict__ offs,
    const int* __restrict__ rowmap, const float* __restrict__ wgtm)
{
  int e = blockIdx.z;
  int cnt = counts[e];
  int m0 = blockIdx.y * 128;
  if (m0 >= cnt) return;
  int off = offs[e];
  int n0 = blockIdx.x * 128;
  const u16* Bt = W2t + (size_t)e * CC * DFFN;
  __shared__ u16 As[128 * 32];
  __shared__ u16 Bs[128 * 32];
  int tid = threadIdx.x;
  int lane = tid & 63, wave = tid >> 6;
  int wm = wave & 1, wn = wave >> 1;
  int ra = tid >> 2, ka = (tid & 3) * 8;
  int r0 = m0 + ra, r1i = m0 + ra + 64;
  const u16* pa0 = (r0  < cnt) ? H + (size_t)(off + r0)  * DFFN + ka : nullptr;
  const u16* pa1 = (r1i < cnt) ? H + (size_t)(off + r1i) * DFFN + ka : nullptr;
  const u16* pb0 = Bt + (size_t)(n0 + ra)      * DFFN + ka;
  const u16* pb1 = Bt + (size_t)(n0 + ra + 64) * DFFN + ka;
  floatx4 acc[4][4] = {};
  int el = lane & 15, eq = lane >> 4;
  uint4 z4 = {0u, 0u, 0u, 0u};
  for (int k0 = 0; k0 < DFFN; k0 += 32){
    __syncthreads();
    uint4 va0 = pa0 ? *(const uint4*)(pa0 + k0) : z4;
    uint4 va1 = pa1 ? *(const uint4*)(pa1 + k0) : z4;
    uint4 vb0 = *(const uint4*)(pb0 + k0);
    uint4 vb1 = *(const uint4*)(pb1 + k0);
    *(uint4*)&As[(size_t)ra * 32 + ka]        = va0;
    *(uint4*)&As[(size_t)(ra + 64) * 32 + ka] = va1;
    *(uint4*)&Bs[(size_t)ra * 32 + ka]        = vb0;
    *(uint4*)&Bs[(size_t)(ra + 64) * 32 + ka] = vb1;
    __syncthreads();
    short8 fa[4], fb[4];
    #pragma unroll
    for (int t = 0; t < 4; ++t)
      fa[t] = *(const short8*)&As[(size_t)(wm*64 + t*16 + el) * 32 + eq*8];
    #pragma unroll
    for (int t = 0; t < 4; ++t)
      fb[t] = *(const short8*)&Bs[(size_t)(wn*64 + t*16 + el) * 32 + eq*8];
    #pragma unroll
    for (int mt = 0; mt < 4; ++mt)
      #pragma unroll
      for (int nt = 0; nt < 4; ++nt)
        acc[mt][nt] = __builtin_amdgcn_mfma_f32_16x16x32_bf16(fa[mt], fb[nt], acc[mt][nt], 0, 0, 0);
  }
  #pragma unroll
  for (int mt = 0; mt < 4; ++mt){
    #pragma unroll
    for (int nt = 0; nt < 4; ++nt){
      int col = n0 + wn*64 + nt*16 + el;
      float bv = b2[(size_t)e * CC + col];
      #pragma unroll
      for (int r = 0; r < 4; ++r){
        int row = m0 + wm*64 + mt*16 + eq*4 + r;
        if (row < cnt){
          int slot = off + row;
          int tok = rowmap[slot];
          float wv = wgtm[slot];
          atomicAdd(&Out[(size_t)tok * CC + col], wv * (acc[mt][nt][r] + bv));
        }
      }
    }
  }
}

// =====================================================================================
extern "C" void kernel_launch(void* const* d_in, const int* in_sizes, int n_in,
                              void* d_out, int out_size, void* d_ws, size_t ws_size,
                              hipStream_t stream)
{
  const float* x     = (const float*)d_in[0];
  const float* ln1w  = (const float*)d_in[1];
  const float* ln1b  = (const float*)d_in[2];
  const float* Wattn = (const float*)d_in[3];
  const float* battn = (const float*)d_in[4];
  const float* Wproj = (const float*)d_in[5];
  const float* bproj = (const float*)d_in[6];
  const float* ln2w  = (const float*)d_in[7];
  const float* ln2b  = (const float*)d_in[8];
  const float* Wrout = (const float*)d_in[9];
  const float* W1    = (const float*)d_in[10];
  const float* b1    = (const float*)d_in[11];
  const float* W2    = (const float*)d_in[12];
  const float* b2    = (const float*)d_in[13];
  float* out = (float*)d_out;

  char* w = (char*)d_ws;
  auto alloc = [&](size_t bytes)->char* {
    char* p = w; w += (bytes + 255) & ~(size_t)255; return p;
  };
  u16* wat[3]; for (int i = 0; i < 3; ++i) wat[i] = (u16*)alloc((size_t)C3 * CC * 2);
  u16* wpt[3]; for (int i = 0; i < 3; ++i) wpt[i] = (u16*)alloc((size_t)CC * CC * 2);
  u16* w1t = (u16*)alloc((size_t)EE * DFFN * CC * 2);
  u16* w2t = (u16*)alloc((size_t)EE * CC * DFFN * 2);
  u16* xs[3]; for (int i = 0; i < 3; ++i) xs[i] = (u16*)alloc((size_t)NTOK * CC * 2);
  float* qkv   = (float*)alloc((size_t)NTOK * C3 * 4);
  float* opart = (float*)alloc((size_t)4 * NROW * HD * 4);
  float* mpart = (float*)alloc((size_t)4 * NROW * 4);
  float* lpart = (float*)alloc((size_t)4 * NROW * 4);
  float* x2    = (float*)alloc((size_t)NTOK * CC * 4);
  float* xn2   = (float*)alloc((size_t)NTOK * CC * 4);
  u16*   xn2b  = (u16*)alloc((size_t)NTOK * CC * 2);
  int*   eids  = (int*)alloc(NSLOT * 4);
  float* wts   = (float*)alloc(NSLOT * 4);
  int* counts  = (int*)alloc(256);
  int* offs    = (int*)alloc(256);
  int* curs    = (int*)alloc(256);
  int* rowmap  = (int*)alloc(NSLOT * 4);
  float* wgtm  = (float*)alloc(NSLOT * 4);
  // aliases (disjoint lifetimes): y-splits reuse xn-splits; H reuses opart (both 50.3 MB)
  u16* ys[3] = { xs[0], xs[1], xs[2] };
  u16* Hbuf = (u16*)opart;

  // 1) weight conversion (+transpose to [N][K] bf16; 3-split for fp32-accuracy path)
  hipLaunchKernelGGL((transpose_split<3>), dim3(C3/32, CC/32, 1), dim3(256), 0, stream,
                     Wattn, wat[0], wat[1], wat[2], CC, C3);
  hipLaunchKernelGGL((transpose_split<3>), dim3(CC/32, CC/32, 1), dim3(256), 0, stream,
                     Wproj, wpt[0], wpt[1], wpt[2], CC, CC);
  hipLaunchKernelGGL((transpose_split<1>), dim3(DFFN/32, CC/32, EE), dim3(256), 0, stream,
                     W1, w1t, (u16*)nullptr, (u16*)nullptr, CC, DFFN);
  hipLaunchKernelGGL((transpose_split<1>), dim3(CC/32, DFFN/32, EE), dim3(256), 0, stream,
                     W2, w2t, (u16*)nullptr, (u16*)nullptr, DFFN, CC);
  // 2) LN1 -> 3-split xn
  hipLaunchKernelGGL(ln_kernel, dim3(NTOK), dim3(256), 0, stream,
                     x, ln1w, ln1b, (float*)nullptr, xs[0], xs[1], xs[2]);
  // 3) qkv = xn @ W_attn + b_attn, 6-pass split-bf16 (fp32-class accuracy)
  hipLaunchKernelGGL((gemm_dense<0>), dim3(C3/128, NTOK/128), dim3(256), 0, stream,
                     xs[0], wat[0], qkv, battn, NTOK, C3, CC);
  {
    const int pi[5] = {1, 0, 1, 2, 0}, pj[5] = {0, 1, 1, 0, 2};
    for (int p = 0; p < 5; ++p)
      hipLaunchKernelGGL((gemm_dense<1>), dim3(C3/128, NTOK/128), dim3(256), 0, stream,
                         xs[pi[p]], wat[pj[p]], qkv, (const float*)nullptr, NTOK, C3, CC);
  }
  // 4) fp32 causal flash attention (key-split x4) -> y (3-split bf16)
  hipLaunchKernelGGL(flash1, dim3(16, 4, BB*HH), dim3(64), 0, stream, qkv, opart, mpart, lpart);
  hipLaunchKernelGGL(flash2, dim3(NROW*HD/256), dim3(256), 0, stream,
                     opart, mpart, lpart, ys[0], ys[1], ys[2]);
  // 5) x2 = x + y @ W_proj + b_proj (6-pass)
  hipMemcpyAsync(x2, x, (size_t)NTOK * CC * 4, hipMemcpyDeviceToDevice, stream);
  hipLaunchKernelGGL((gemm_dense<1>), dim3(CC/128, NTOK/128), dim3(256), 0, stream,
                     ys[0], wpt[0], x2, bproj, NTOK, CC, CC);
  {
    const int pi[5] = {1, 0, 1, 2, 0}, pj[5] = {0, 1, 1, 0, 2};
    for (int p = 0; p < 5; ++p)
      hipLaunchKernelGGL((gemm_dense<1>), dim3(CC/128, NTOK/128), dim3(256), 0, stream,
                         ys[pi[p]], wpt[pj[p]], x2, (const float*)nullptr, NTOK, CC, CC);
  }
  // 6) LN2 -> xn2 fp32 (router) + single bf16 (MoE input)
  hipLaunchKernelGGL(ln_kernel, dim3(NTOK), dim3(256), 0, stream,
                     x2, ln2w, ln2b, xn2, xn2b, (u16*)nullptr, (u16*)nullptr);
  // 7) router (fp32 exact top-2) + expert gather lists
  hipLaunchKernelGGL(router_kernel, dim3(NTOK/4), dim3(256), 0, stream, xn2, Wrout, eids, wts);
  hipLaunchKernelGGL(moe_count, dim3(1), dim3(256), 0, stream, eids, counts, offs, curs);
  hipLaunchKernelGGL(moe_scatter, dim3(NSLOT/256), dim3(256), 0, stream, eids, wts, curs, rowmap, wgtm);
  // 8) out = x2 + xn2  (MoE adds on top)
  hipLaunchKernelGGL(add2, dim3(NTOK*CC/256), dim3(256), 0, stream, x2, xn2, out, NTOK*CC);
  // 9) MoE expert FFN (bf16 MFMA, gathered rows, weighted atomic scatter-add)
  hipLaunchKernelGGL(gemm_moe1, dim3(DFFN/128, 32, EE), dim3(256), 0, stream,
                     xn2b, w1t, b1, Hbuf, counts, offs, rowmap);
  hipLaunchKernelGGL(gemm_moe2, dim3(CC/128, 32, EE), dim3(256), 0, stream,
                     Hbuf, w2t, b2, out, counts, offs, rowmap, wgtm);
}

// Round 2
// 1465.719 us; speedup vs baseline: 1.1200x; 1.1200x over previous
//
#include <hip/hip_runtime.h>
#include <math.h>

#define CC    768
#define C3    2304
#define K6    4608   /* 6 concatenated 768-chunks for split-bf16 single-pass GEMM */
#define TT    1024
#define BB    4
#define HH    12
#define HD    64
#define EE    16
#define DFFN  3072
#define NTOK  4096
#define NROW  49152   /* B*H*T */
#define NSLOT 8192    /* NTOK * top-2 */

typedef unsigned short u16;
typedef unsigned int   u32;
typedef __attribute__((ext_vector_type(8))) short short8;
typedef __attribute__((ext_vector_type(4))) float floatx4;

__device__ __forceinline__ u16 f2bf(float f){
  u32 x = __builtin_bit_cast(u32, f);
  x += 0x7fffu + ((x >> 16) & 1u);   // RNE
  return (u16)(x >> 16);
}
__device__ __forceinline__ float bf2f(u16 u){
  return __builtin_bit_cast(float, (u32)u << 16);
}
__device__ __forceinline__ float gelu_exact(float v){
  return 0.5f * v * (1.f + erff(v * 0.70710678118654752440f));
}

// A-side chunk layout: [a0,a0,a1,a1,a0,a2]  B-side: [b0,b1,b0,b1,b2,b0]
// -> per-chunk products: a0b0, a0b1, a1b0, a1b1, a0b2, a2b0 (all terms >= 2^-18)
__device__ __forceinline__ void writeA6(u16* row, int c, float v){
  u16 h0 = f2bf(v); float r = v - bf2f(h0);
  u16 h1 = f2bf(r); u16 h2 = f2bf(r - bf2f(h1));
  row[c] = h0; row[768 + c] = h0; row[3072 + c] = h0;
  row[1536 + c] = h1; row[2304 + c] = h1;
  row[3840 + c] = h2;
}
__device__ __forceinline__ void writeB6(u16* base, float v){
  u16 h0 = f2bf(v); float r = v - bf2f(h0);
  u16 h1 = f2bf(r); u16 h2 = f2bf(r - bf2f(h1));
  base[0] = h0; base[1536] = h0; base[3840] = h0;
  base[768] = h1; base[2304] = h1;
  base[3072] = h2;
}

// ---------------- fp32 -> bf16 transpose. MODE 0: plain [z][Cn][R].
// MODE 1: B-side 6-chunk split layout [Cn][K6] (row=src col, col=chunk*768+src row)
template<int MODE>
__global__ __launch_bounds__(256) void transpose_split(const float* __restrict__ src,
    u16* __restrict__ d0, int R, int Cn)
{
  __shared__ float tile[32][33];
  int z = blockIdx.z;
  const float* s = src + (size_t)z * R * Cn;
  int c0 = blockIdx.x * 32, r0 = blockIdx.y * 32;
  int tx = threadIdx.x & 31, ty = threadIdx.x >> 5;
  #pragma unroll
  for (int j = 0; j < 4; ++j)
    tile[ty + j*8][tx] = s[(size_t)(r0 + ty + j*8) * Cn + c0 + tx];
  __syncthreads();
  #pragma unroll
  for (int j = 0; j < 4; ++j){
    float v = tile[tx][ty + j*8];
    if (MODE == 1){
      writeB6(d0 + (size_t)(c0 + ty + j*8) * K6 + (r0 + tx), v);
    } else {
      d0[(size_t)z * R * Cn + (size_t)(c0 + ty + j*8) * R + r0 + tx] = f2bf(v);
    }
  }
}

// ---------------- LayerNorm. MODE 0: fp32 out + single bf16 out (stride CC).
// MODE 1: 6-chunk A-side split out (stride K6).
template<int MODE>
__global__ __launch_bounds__(256) void ln_kernel(const float* __restrict__ x,
    const float* __restrict__ gw, const float* __restrict__ gb,
    float* __restrict__ of, u16* __restrict__ o0)
{
  int tok = blockIdx.x, tid = threadIdx.x;
  const float* xr = x + (size_t)tok * CC;
  float v0 = xr[tid], v1 = xr[tid + 256], v2 = xr[tid + 512];
  __shared__ float r1[4], r2[4];
  __shared__ float mus, rss;
  float s = v0 + v1 + v2;
  #pragma unroll
  for (int off = 32; off >= 1; off >>= 1) s += __shfl_down(s, off);
  if ((tid & 63) == 0) r1[tid >> 6] = s;
  __syncthreads();
  if (tid == 0) mus = (r1[0] + r1[1] + r1[2] + r1[3]) * (1.f / 768.f);
  __syncthreads();
  float mu = mus;
  float d0 = v0 - mu, d1 = v1 - mu, d2 = v2 - mu;
  float t = d0*d0 + d1*d1 + d2*d2;
  #pragma unroll
  for (int off = 32; off >= 1; off >>= 1) t += __shfl_down(t, off);
  if ((tid & 63) == 0) r2[tid >> 6] = t;
  __syncthreads();
  if (tid == 0) rss = rsqrtf((r2[0] + r2[1] + r2[2] + r2[3]) * (1.f / 768.f) + 1e-5f);
  __syncthreads();
  float rstd = rss;
  float dv[3] = {d0, d1, d2};
  #pragma unroll
  for (int i = 0; i < 3; ++i){
    int c = tid + i * 256;
    float vv = dv[i] * rstd * gw[c] + gb[c];
    if (MODE == 1){
      writeA6(o0 + (size_t)tok * K6, c, vv);
    } else {
      size_t idx = (size_t)tok * CC + c;
      of[idx] = vv;
      o0[idx] = f2bf(vv);
    }
  }
}

// ---------------- dense bf16 NT GEMM: C[M][N] (+)= A[M][K] * Bt[N][K]^T + bias ------
template<int BETA>
__global__ __launch_bounds__(256) void gemm_dense(
    const u16* __restrict__ A, const u16* __restrict__ Bt,
    float* __restrict__ C, const float* __restrict__ bias,
    int M, int N, int K)
{
  __shared__ u16 As[128 * 32];
  __shared__ u16 Bs[128 * 32];
  int tid = threadIdx.x;
  int lane = tid & 63, wave = tid >> 6;
  int wm = wave & 1, wn = wave >> 1;
  int m0 = blockIdx.y * 128, n0 = blockIdx.x * 128;
  int ra = tid >> 2, ka = (tid & 3) * 8;
  const u16* pa0 = A  + (size_t)(m0 + ra)      * K + ka;
  const u16* pa1 = A  + (size_t)(m0 + ra + 64) * K + ka;
  const u16* pb0 = Bt + (size_t)(n0 + ra)      * K + ka;
  const u16* pb1 = Bt + (size_t)(n0 + ra + 64) * K + ka;
  floatx4 acc[4][4] = {};
  int el = lane & 15, eq = lane >> 4;
  for (int k0 = 0; k0 < K; k0 += 32){
    __syncthreads();
    uint4 va0 = *(const uint4*)(pa0 + k0);
    uint4 va1 = *(const uint4*)(pa1 + k0);
    uint4 vb0 = *(const uint4*)(pb0 + k0);
    uint4 vb1 = *(const uint4*)(pb1 + k0);
    *(uint4*)&As[(size_t)ra * 32 + ka]        = va0;
    *(uint4*)&As[(size_t)(ra + 64) * 32 + ka] = va1;
    *(uint4*)&Bs[(size_t)ra * 32 + ka]        = vb0;
    *(uint4*)&Bs[(size_t)(ra + 64) * 32 + ka] = vb1;
    __syncthreads();
    short8 fa[4], fb[4];
    #pragma unroll
    for (int t = 0; t < 4; ++t)
      fa[t] = *(const short8*)&As[(size_t)(wm*64 + t*16 + el) * 32 + eq*8];
    #pragma unroll
    for (int t = 0; t < 4; ++t)
      fb[t] = *(const short8*)&Bs[(size_t)(wn*64 + t*16 + el) * 32 + eq*8];
    #pragma unroll
    for (int mt = 0; mt < 4; ++mt)
      #pragma unroll
      for (int nt = 0; nt < 4; ++nt)
        acc[mt][nt] = __builtin_amdgcn_mfma_f32_16x16x32_bf16(fa[mt], fb[nt], acc[mt][nt], 0, 0, 0);
  }
  #pragma unroll
  for (int mt = 0; mt < 4; ++mt){
    #pragma unroll
    for (int nt = 0; nt < 4; ++nt){
      int col = n0 + wn*64 + nt*16 + el;
      float bv = bias ? bias[col] : 0.f;
      #pragma unroll
      for (int r = 0; r < 4; ++r){
        int row = m0 + wm*64 + mt*16 + eq*4 + r;
        size_t idx = (size_t)row * N + col;
        float val = acc[mt][nt][r] + bv;
        if (BETA) val += C[idx];
        C[idx] = val;
      }
    }
  }
}

// ---------------- fp32 flash attention ----------------
// grid (4 rowblocks of 256, 4 key-splits, B*H), block 256 (4 waves share K/V tile).
// Branchless chunked online softmax in log2 domain. Fully-masked partials keep
// m=-1e30 and are annihilated by the merge (e = exp2(m-M) = 0).
__global__ __launch_bounds__(256) void flash1(const float* __restrict__ qkv,
    float* __restrict__ opart, float* __restrict__ mpart, float* __restrict__ lpart)
{
  __shared__ float Ks[64 * 64];
  __shared__ float Vs[64 * 64];
  int tid = threadIdx.x;
  int lane = tid & 63, wv = tid >> 6;
  int rb = blockIdx.x, split = blockIdx.y, bh = blockIdx.z;
  int b = bh / HH, h = bh % HH;
  int r = rb*256 + wv*64 + lane;
  const float* qr = qkv + (size_t)(b * TT + r) * C3 + h * HD;
  const float sc = 0.18033688011112042f;   // 0.125 * log2(e): softmax in log2 domain
  floatx4 q[16], o[16];
  #pragma unroll
  for (int i = 0; i < 16; ++i){
    q[i] = (*(const floatx4*)(qr + i*4)) * sc;
    o[i] = (floatx4){0.f, 0.f, 0.f, 0.f};
  }
  float m = -1e30f, l = 0.f;
  int wmax = rb*256 + wv*64 + 63;
  int lastT = rb*4 + 3;
  for (int t = split; t <= lastT; t += 4){
    __syncthreads();
    int kt0 = t * 64;
    #pragma unroll
    for (int i = 0; i < 4; ++i){
      int idx = i*256 + tid;
      int j = idx >> 4, ch = idx & 15;
      size_t base = (size_t)(b * TT + kt0 + j) * C3 + h * HD + ch * 4;
      *(floatx4*)&Ks[j*64 + ch*4] = *(const floatx4*)(qkv + base + CC);
      *(floatx4*)&Vs[j*64 + ch*4] = *(const floatx4*)(qkv + base + 2*CC);
    }
    __syncthreads();
    if (kt0 > wmax) continue;        // wave-uniform skip; barrier counts still match
    #pragma unroll 1
    for (int c = 0; c < 8; ++c){
      float s[8];
      #pragma unroll
      for (int jj = 0; jj < 8; ++jj){
        int j = c*8 + jj;
        const floatx4* kr = (const floatx4*)&Ks[j*64];
        float a0 = 0.f, a1 = 0.f, a2 = 0.f, a3 = 0.f;
        #pragma unroll
        for (int i = 0; i < 16; i += 4){
          floatx4 k0 = kr[i], k1 = kr[i+1], k2 = kr[i+2], k3 = kr[i+3];
          a0 += q[i  ].x*k0.x + q[i  ].y*k0.y + q[i  ].z*k0.z + q[i  ].w*k0.w;
          a1 += q[i+1].x*k1.x + q[i+1].y*k1.y + q[i+1].z*k1.z + q[i+1].w*k1.w;
          a2 += q[i+2].x*k2.x + q[i+2].y*k2.y + q[i+2].z*k2.z + q[i+2].w*k2.w;
          a3 += q[i+3].x*k3.x + q[i+3].y*k3.y + q[i+3].z*k3.z + q[i+3].w*k3.w;
        }
        float sv = (a0 + a1) + (a2 + a3);
        s[jj] = (kt0 + j <= r) ? sv : -1e30f;
      }
      float mn = m;
      #pragma unroll
      for (int jj = 0; jj < 8; ++jj) mn = fmaxf(mn, s[jj]);
      float al = exp2f(m - mn);
      m = mn;
      l *= al;
      #pragma unroll
      for (int i = 0; i < 16; ++i) o[i] *= al;
      #pragma unroll
      for (int jj = 0; jj < 8; ++jj){
        int j = c*8 + jj;
        float p = exp2f(s[jj] - mn);
        l += p;
        const floatx4* vr = (const floatx4*)&Vs[j*64];
        #pragma unroll
        for (int i = 0; i < 16; ++i) o[i] += p * vr[i];
      }
    }
  }
  size_t idx = (size_t)split * NROW + (size_t)bh * TT + r;
  mpart[idx] = m; lpart[idx] = l;
  float* op = opart + idx * 64;
  #pragma unroll
  for (int i = 0; i < 16; ++i) *(floatx4*)(op + i*4) = o[i];
}

// merge 4 key-split partials -> y, written as 6-chunk A-side split layout [tok][K6]
__global__ __launch_bounds__(256) void flash2(const float* __restrict__ opart,
    const float* __restrict__ mpart, const float* __restrict__ lpart,
    u16* __restrict__ yA)
{
  int gid = blockIdx.x * 256 + threadIdx.x;
  int row = gid >> 6, d = gid & 63;
  float m0 = mpart[row],          m1 = mpart[NROW + row];
  float m2 = mpart[2*NROW + row], m3 = mpart[3*NROW + row];
  float M = fmaxf(fmaxf(m0, m1), fmaxf(m2, m3));
  float e0 = exp2f(m0 - M), e1 = exp2f(m1 - M), e2 = exp2f(m2 - M), e3 = exp2f(m3 - M);
  float den = lpart[row]*e0 + lpart[NROW+row]*e1 + lpart[2*NROW+row]*e2 + lpart[3*NROW+row]*e3;
  float num = opart[(size_t)row*64 + d]            * e0
            + opart[(size_t)(NROW   + row)*64 + d] * e1
            + opart[(size_t)(2*NROW + row)*64 + d] * e2
            + opart[(size_t)(3*NROW + row)*64 + d] * e3;
  float y = num / den;
  int bh = row >> 10, t = row & 1023;
  int b = bh / HH, h = bh % HH;
  writeA6(yA + (size_t)(b * TT + t) * K6, h * HD + d, y);
}

// ---------------- router: fp32 logits, softmax, top-2 ----------------
__global__ __launch_bounds__(256) void router_kernel(const float* __restrict__ xn2,
    const float* __restrict__ Wr, int* __restrict__ eids, float* __restrict__ wts)
{
  int wave = threadIdx.x >> 6, lane = threadIdx.x & 63;
  int tok = blockIdx.x * 4 + wave;
  int g = lane >> 4, e = lane & 15;
  const float* xr = xn2 + (size_t)tok * CC;
  float s = 0.f;
  for (int c4 = 0; c4 < 192; ++c4){
    int c = c4 * 4 + g;
    s += xr[c] * Wr[c * EE + e];
  }
  s += __shfl_xor(s, 16);
  s += __shfl_xor(s, 32);              // every lane: logit for expert (lane&15)
  float mx = s;
  #pragma unroll
  for (int off = 1; off < 16; off <<= 1) mx = fmaxf(mx, __shfl_xor(mx, off));
  float p = expf(s - mx);
  float Z = p;
  #pragma unroll
  for (int off = 1; off < 16; off <<= 1) Z += __shfl_xor(Z, off);
  p /= Z;
  float best = -1.f; int bi = 0;
  for (int ee = 0; ee < 16; ++ee){
    float pe = __shfl(p, ee);
    if (pe > best){ best = pe; bi = ee; }
  }
  float sec = -1.f; int si = 0;
  for (int ee = 0; ee < 16; ++ee){
    float pe = __shfl(p, ee);
    if (ee != bi && pe > sec){ sec = pe; si = ee; }
  }
  if (lane == 0){
    eids[tok*2] = bi;  eids[tok*2+1] = si;
    wts [tok*2] = best; wts[tok*2+1] = sec;
  }
}

__global__ __launch_bounds__(256) void moe_count(const int* __restrict__ eids,
    int* __restrict__ counts, int* __restrict__ offs, int* __restrict__ curs)
{
  __shared__ int lc[EE];
  int tid = threadIdx.x;
  if (tid < EE) lc[tid] = 0;
  __syncthreads();
  for (int i = tid; i < NSLOT; i += 256) atomicAdd(&lc[eids[i]], 1);
  __syncthreads();
  if (tid == 0){
    int run = 0;
    for (int e = 0; e < EE; ++e){
      counts[e] = lc[e]; offs[e] = run; curs[e] = run; run += lc[e];
    }
    offs[EE] = run;
  }
}

__global__ __launch_bounds__(256) void moe_scatter(const int* __restrict__ eids,
    const float* __restrict__ wts, int* __restrict__ curs,
    int* __restrict__ rowmap, float* __restrict__ wgtm)
{
  int i = blockIdx.x * 256 + threadIdx.x;
  int e = eids[i];
  int pos = atomicAdd(&curs[e], 1);
  rowmap[pos] = i >> 1;
  wgtm[pos] = wts[i];
}

__global__ __launch_bounds__(256) void add2(const float* __restrict__ a,
    const float* __restrict__ b, float* __restrict__ o, int n)
{
  int i = blockIdx.x * 256 + threadIdx.x;
  if (i < n) o[i] = a[i] + b[i];
}

// ---------------- MoE expert GEMM1: H = gelu(gather(xn2b) @ W1t^T + b1) ----------------
__global__ __launch_bounds__(256) void gemm_moe1(
    const u16* __restrict__ Xb, const u16* __restrict__ W1t, const float* __restrict__ b1,
    u16* __restrict__ H, const int* __restrict__ counts, const int* __restrict__ offs,
    const int* __restrict__ rowmap)
{
  int e = blockIdx.z;
  int cnt = counts[e];
  int m0 = blockIdx.y * 128;
  if (m0 >= cnt) return;
  int off = offs[e];
  int n0 = blockIdx.x * 128;
  const u16* Bt = W1t + (size_t)e * DFFN * CC;
  __shared__ u16 As[128 * 32];
  __shared__ u16 Bs[128 * 32];
  int tid = threadIdx.x;
  int lane = tid & 63, wave = tid >> 6;
  int wm = wave & 1, wn = wave >> 1;
  int ra = tid >> 2, ka = (tid & 3) * 8;
  int r0 = m0 + ra, r1i = m0 + ra + 64;
  const u16* pa0 = (r0  < cnt) ? Xb + (size_t)rowmap[off + r0]  * CC + ka : nullptr;
  const u16* pa1 = (r1i < cnt) ? Xb + (size_t)rowmap[off + r1i] * CC + ka : nullptr;
  const u16* pb0 = Bt + (size_t)(n0 + ra)      * CC + ka;
  const u16* pb1 = Bt + (size_t)(n0 + ra + 64) * CC + ka;
  floatx4 acc[4][4] = {};
  int el = lane & 15, eq = lane >> 4;
  uint4 z4 = {0u, 0u, 0u, 0u};
  for (int k0 = 0; k0 < CC; k0 += 32){
    __syncthreads();
    uint4 va0 = pa0 ? *(const uint4*)(pa0 + k0) : z4;
    uint4 va1 = pa1 ? *(const uint4*)(pa1 + k0) : z4;
    uint4 vb0 = *(const uint4*)(pb0 + k0);
    uint4 vb1 = *(const uint4*)(pb1 + k0);
    *(uint4*)&As[(size_t)ra * 32 + ka]        = va0;
    *(uint4*)&As[(size_t)(ra + 64) * 32 + ka] = va1;
    *(uint4*)&Bs[(size_t)ra * 32 + ka]        = vb0;
    *(uint4*)&Bs[(size_t)(ra + 64) * 32 + ka] = vb1;
    __syncthreads();
    short8 fa[4], fb[4];
    #pragma unroll
    for (int t = 0; t < 4; ++t)
      fa[t] = *(const short8*)&As[(size_t)(wm*64 + t*16 + el) * 32 + eq*8];
    #pragma unroll
    for (int t = 0; t < 4; ++t)
      fb[t] = *(const short8*)&Bs[(size_t)(wn*64 + t*16 + el) * 32 + eq*8];
    #pragma unroll
    for (int mt = 0; mt < 4; ++mt)
      #pragma unroll
      for (int nt = 0; nt < 4; ++nt)
        acc[mt][nt] = __builtin_amdgcn_mfma_f32_16x16x32_bf16(fa[mt], fb[nt], acc[mt][nt], 0, 0, 0);
  }
  #pragma unroll
  for (int mt = 0; mt < 4; ++mt){
    #pragma unroll
    for (int nt = 0; nt < 4; ++nt){
      int col = n0 + wn*64 + nt*16 + el;
      float bv = b1[(size_t)e * DFFN + col];
      #pragma unroll
      for (int r = 0; r < 4; ++r){
        int row = m0 + wm*64 + mt*16 + eq*4 + r;
        if (row < cnt)
          H[(size_t)(off + row) * DFFN + col] = f2bf(gelu_exact(acc[mt][nt][r] + bv));
      }
    }
  }
}

// ---------------- MoE expert GEMM2: out[tok] += w * (H @ W2t^T + b2) ----------------
__global__ __launch_bounds__(256) void gemm_moe2(
    const u16* __restrict__ H, const u16* __restrict__ W2t, const float* __restrict__ b2,
    float* __restrict__ Out, const int* __restrict__ counts, const int* __restrict__ offs,
    const int* __restrict__ rowmap, const float* __restrict__ wgtm)
{
  int e = blockIdx.z;
  int cnt = counts[e];
  int m0 = blockIdx.y * 128;
  if (m0 >= cnt) return;
  int off = offs[e];
  int n0 = blockIdx.x * 128;
  const u16* Bt = W2t + (size_t)e * CC * DFFN;
  __shared__ u16 As[128 * 32];
  __shared__ u16 Bs[128 * 32];
  int tid = threadIdx.x;
  int lane = tid & 63, wave = tid >> 6;
  int wm = wave & 1, wn = wave >> 1;
  int ra = tid >> 2, ka = (tid & 3) * 8;
  int r0 = m0 + ra, r1i = m0 + ra + 64;
  const u16* pa0 = (r0  < cnt) ? H + (size_t)(off + r0)  * DFFN + ka : nullptr;
  const u16* pa1 = (r1i < cnt) ? H + (size_t)(off + r1i) * DFFN + ka : nullptr;
  const u16* pb0 = Bt + (size_t)(n0 + ra)      * DFFN + ka;
  const u16* pb1 = Bt + (size_t)(n0 + ra + 64) * DFFN + ka;
  floatx4 acc[4][4] = {};
  int el = lane & 15, eq = lane >> 4;
  uint4 z4 = {0u, 0u, 0u, 0u};
  for (int k0 = 0; k0 < DFFN; k0 += 32){
    __syncthreads();
    uint4 va0 = pa0 ? *(const uint4*)(pa0 + k0) : z4;
    uint4 va1 = pa1 ? *(const uint4*)(pa1 + k0) : z4;
    uint4 vb0 = *(const uint4*)(pb0 + k0);
    uint4 vb1 = *(const uint4*)(pb1 + k0);
    *(uint4*)&As[(size_t)ra * 32 + ka]        = va0;
    *(uint4*)&As[(size_t)(ra + 64) * 32 + ka] = va1;
    *(uint4*)&Bs[(size_t)ra * 32 + ka]        = vb0;
    *(uint4*)&Bs[(size_t)(ra + 64) * 32 + ka] = vb1;
    __syncthreads();
    short8 fa[4], fb[4];
    #pragma unroll
    for (int t = 0; t < 4; ++t)
      fa[t] = *(const short8*)&As[(size_t)(wm*64 + t*16 + el) * 32 + eq*8];
    #pragma unroll
    for (int t = 0; t < 4; ++t)
      fb[t] = *(const short8*)&Bs[(size_t)(wn*64 + t*16 + el) * 32 + eq*8];
    #pragma unroll
    for (int mt = 0; mt < 4; ++mt)
      #pragma unroll
      for (int nt = 0; nt < 4; ++nt)
        acc[mt][nt] = __builtin_amdgcn_mfma_f32_16x16x32_bf16(fa[mt], fb[nt], acc[mt][nt], 0, 0, 0);
  }
  #pragma unroll
  for (int mt = 0; mt < 4; ++mt){
    #pragma unroll
    for (int nt = 0; nt < 4; ++nt){
      int col = n0 + wn*64 + nt*16 + el;
      float bv = b2[(size_t)e * CC + col];
      #pragma unroll
      for (int r = 0; r < 4; ++r){
        int row = m0 + wm*64 + mt*16 + eq*4 + r;
        if (row < cnt){
          int slot = off + row;
          int tok = rowmap[slot];
          float wv = wgtm[slot];
          atomicAdd(&Out[(size_t)tok * CC + col], wv * (acc[mt][nt][r] + bv));
        }
      }
    }
  }
}

// =====================================================================================
extern "C" void kernel_launch(void* const* d_in, const int* in_sizes, int n_in,
                              void* d_out, int out_size, void* d_ws, size_t ws_size,
                              hipStream_t stream)
{
  const float* x     = (const float*)d_in[0];
  const float* ln1w  = (const float*)d_in[1];
  const float* ln1b  = (const float*)d_in[2];
  const float* Wattn = (const float*)d_in[3];
  const float* battn = (const float*)d_in[4];
  const float* Wproj = (const float*)d_in[5];
  const float* bproj = (const float*)d_in[6];
  const float* ln2w  = (const float*)d_in[7];
  const float* ln2b  = (const float*)d_in[8];
  const float* Wrout = (const float*)d_in[9];
  const float* W1    = (const float*)d_in[10];
  const float* b1    = (const float*)d_in[11];
  const float* W2    = (const float*)d_in[12];
  const float* b2    = (const float*)d_in[13];
  float* out = (float*)d_out;

  char* w = (char*)d_ws;
  auto alloc = [&](size_t bytes)->char* {
    char* p = w; w += (bytes + 255) & ~(size_t)255; return p;
  };
  u16* watp  = (u16*)alloc((size_t)C3 * K6 * 2);        // 21.2 MB, B-side 6-chunk
  u16* wptp  = (u16*)alloc((size_t)CC * K6 * 2);        //  7.1 MB
  u16* w1t   = (u16*)alloc((size_t)EE * DFFN * CC * 2); // 75.5 MB
  u16* w2t   = (u16*)alloc((size_t)EE * CC * DFFN * 2); // 75.5 MB
  // region R1 (50.3 MB): xA' (37.7) -> opart (50.3) -> Hbuf (50.3), disjoint lifetimes
  char* R1   = alloc((size_t)4 * NROW * HD * 4);
  u16*   xA    = (u16*)R1;
  float* opart = (float*)R1;
  u16*   Hbuf  = (u16*)R1;
  // region R2 (37.7 MB): qkv fp32 -> yA' bf16, disjoint lifetimes
  char* R2   = alloc((size_t)NTOK * C3 * 4);
  float* qkv = (float*)R2;
  u16*   yA  = (u16*)R2;
  float* mpart = (float*)alloc((size_t)4 * NROW * 4);
  float* lpart = (float*)alloc((size_t)4 * NROW * 4);
  float* x2    = (float*)alloc((size_t)NTOK * CC * 4);
  float* xn2   = (float*)alloc((size_t)NTOK * CC * 4);
  u16*   xn2b  = (u16*)alloc((size_t)NTOK * CC * 2);
  int*   eids  = (int*)alloc(NSLOT * 4);
  float* wts   = (float*)alloc(NSLOT * 4);
  int* counts  = (int*)alloc(256);
  int* offs    = (int*)alloc(256);
  int* curs    = (int*)alloc(256);
  int* rowmap  = (int*)alloc(NSLOT * 4);
  float* wgtm  = (float*)alloc(NSLOT * 4);

  // 1) weight conversion: attn/proj -> B-side 6-chunk split layouts; W1/W2 -> plain bf16 [n][k]
  hipLaunchKernelGGL((transpose_split<1>), dim3(C3/32, CC/32, 1), dim3(256), 0, stream,
                     Wattn, watp, CC, C3);
  hipLaunchKernelGGL((transpose_split<1>), dim3(CC/32, CC/32, 1), dim3(256), 0, stream,
                     Wproj, wptp, CC, CC);
  hipLaunchKernelGGL((transpose_split<0>), dim3(DFFN/32, CC/32, EE), dim3(256), 0, stream,
                     W1, w1t, CC, DFFN);
  hipLaunchKernelGGL((transpose_split<0>), dim3(CC/32, DFFN/32, EE), dim3(256), 0, stream,
                     W2, w2t, DFFN, CC);
  // 2) LN1 -> A-side 6-chunk split xA'
  hipLaunchKernelGGL((ln_kernel<1>), dim3(NTOK), dim3(256), 0, stream,
                     x, ln1w, ln1b, (float*)nullptr, xA);
  // 3) qkv = xn @ W_attn + b_attn: ONE K=4608 pass == 6 split-product terms
  hipLaunchKernelGGL((gemm_dense<0>), dim3(C3/128, NTOK/128), dim3(256), 0, stream,
                     xA, watp, qkv, battn, NTOK, C3, K6);
  // 4) fp32 causal flash attention (4 waves/block, key-split x4) -> partials -> yA'
  hipLaunchKernelGGL(flash1, dim3(4, 4, BB*HH), dim3(256), 0, stream, qkv, opart, mpart, lpart);
  hipLaunchKernelGGL(flash2, dim3(NROW*HD/256), dim3(256), 0, stream,
                     opart, mpart, lpart, yA);
  // 5) x2 = x + y @ W_proj + b_proj: ONE K=4608 pass
  hipMemcpyAsync(x2, x, (size_t)NTOK * CC * 4, hipMemcpyDeviceToDevice, stream);
  hipLaunchKernelGGL((gemm_dense<1>), dim3(CC/128, NTOK/128), dim3(256), 0, stream,
                     yA, wptp, x2, bproj, NTOK, CC, K6);
  // 6) LN2 -> xn2 fp32 (router) + single bf16 (MoE input)
  hipLaunchKernelGGL((ln_kernel<0>), dim3(NTOK), dim3(256), 0, stream,
                     x2, ln2w, ln2b, xn2, xn2b);
  // 7) router (fp32 exact top-2) + expert gather lists
  hipLaunchKernelGGL(router_kernel, dim3(NTOK/4), dim3(256), 0, stream, xn2, Wrout, eids, wts);
  hipLaunchKernelGGL(moe_count, dim3(1), dim3(256), 0, stream, eids, counts, offs, curs);
  hipLaunchKernelGGL(moe_scatter, dim3(NSLOT/256), dim3(256), 0, stream, eids, wts, curs, rowmap, wgtm);
  // 8) out = x2 + xn2  (MoE adds on top)
  hipLaunchKernelGGL(add2, dim3(NTOK*CC/256), dim3(256), 0, stream, x2, xn2, out, NTOK*CC);
  // 9) MoE expert FFN (bf16 MFMA, gathered rows, weighted atomic scatter-add)
  hipLaunchKernelGGL(gemm_moe1, dim3(DFFN/128, 32, EE), dim3(256), 0, stream,
                     xn2b, w1t, b1, Hbuf, counts, offs, rowmap);
  hipLaunchKernelGGL(gemm_moe2, dim3(CC/128, 32, EE), dim3(256), 0, stream,
                     Hbuf, w2t, b2, out, counts, offs, rowmap, wgtm);
}

// Round 3
// 1019.297 us; speedup vs baseline: 1.6106x; 1.4380x over previous
//
#include <hip/hip_runtime.h>
#include <math.h>

#define CC    768
#define C3    2304
#define KD    2304   /* dense GEMM K: 3 chunks x 768 (fp16 3-term split) */
#define LDA2  1536   /* compact 2-split row stride: [a0(768) | a1(768)] */
#define TT    1024
#define BB    4
#define HH    12
#define HD    64
#define EE    16
#define DFFN  3072
#define NTOK  4096
#define NSLOT 8192
#define LDP   136    /* flash LDS padded stride (halves) */

typedef unsigned short u16;
typedef unsigned int   u32;
typedef __attribute__((ext_vector_type(8))) short short8;
typedef __attribute__((ext_vector_type(4))) float floatx4;

__device__ __forceinline__ u16 f2bf(float f){
  u32 x = __builtin_bit_cast(u32, f);
  x += 0x7fffu + ((x >> 16) & 1u);   // RNE
  return (u16)(x >> 16);
}
__device__ __forceinline__ u16 f2h(float f){
  _Float16 h = (_Float16)f;
  return __builtin_bit_cast(u16, h);
}
__device__ __forceinline__ float h2f(u16 u){
  return (float)__builtin_bit_cast(_Float16, u);
}
__device__ __forceinline__ float gelu_exact(float v){
  return 0.5f * v * (1.f + erff(v * 0.70710678118654752440f));
}
// x64-scaled fp16 2-way split: v*64 = h0 + h1 (+ <2^-24 rel residual)
__device__ __forceinline__ void split2h(float v, u16& h0, u16& h1){
  float vs = v * 64.f;
  h0 = f2h(vs);
  h1 = f2h(vs - h2f(h0));
}

// ---------------- fp32 -> transpose. MODE 0: plain bf16 [z][Cn][R].
// MODE 1: fp16 2-split x64 [Cn][1536] ([b0|b1])
template<int MODE>
__global__ __launch_bounds__(256) void transpose_split(const float* __restrict__ src,
    u16* __restrict__ d0, int R, int Cn)
{
  __shared__ float tile[32][33];
  int z = blockIdx.z;
  const float* s = src + (size_t)z * R * Cn;
  int c0 = blockIdx.x * 32, r0 = blockIdx.y * 32;
  int tx = threadIdx.x & 31, ty = threadIdx.x >> 5;
  #pragma unroll
  for (int j = 0; j < 4; ++j)
    tile[ty + j*8][tx] = s[(size_t)(r0 + ty + j*8) * Cn + c0 + tx];
  __syncthreads();
  #pragma unroll
  for (int j = 0; j < 4; ++j){
    float v = tile[tx][ty + j*8];
    if (MODE == 1){
      u16 h0, h1; split2h(v, h0, h1);
      size_t base = (size_t)(c0 + ty + j*8) * LDA2 + (r0 + tx);
      d0[base] = h0; d0[base + 768] = h1;
    } else {
      d0[(size_t)z * R * Cn + (size_t)(c0 + ty + j*8) * R + r0 + tx] = f2bf(v);
    }
  }
}

// ---------------- LayerNorm. MODE 0: fp32 out + bf16 out (stride CC).
// MODE 1: fp16 2-split x64 out [tok][1536].
template<int MODE>
__global__ __launch_bounds__(256) void ln_kernel(const float* __restrict__ x,
    const float* __restrict__ gw, const float* __restrict__ gb,
    float* __restrict__ of, u16* __restrict__ o0)
{
  int tok = blockIdx.x, tid = threadIdx.x;
  const float* xr = x + (size_t)tok * CC;
  float v0 = xr[tid], v1 = xr[tid + 256], v2 = xr[tid + 512];
  __shared__ float r1[4], r2[4];
  __shared__ float mus, rss;
  float s = v0 + v1 + v2;
  #pragma unroll
  for (int off = 32; off >= 1; off >>= 1) s += __shfl_down(s, off);
  if ((tid & 63) == 0) r1[tid >> 6] = s;
  __syncthreads();
  if (tid == 0) mus = (r1[0] + r1[1] + r1[2] + r1[3]) * (1.f / 768.f);
  __syncthreads();
  float mu = mus;
  float d0 = v0 - mu, d1 = v1 - mu, d2 = v2 - mu;
  float t = d0*d0 + d1*d1 + d2*d2;
  #pragma unroll
  for (int off = 32; off >= 1; off >>= 1) t += __shfl_down(t, off);
  if ((tid & 63) == 0) r2[tid >> 6] = t;
  __syncthreads();
  if (tid == 0) rss = rsqrtf((r2[0] + r2[1] + r2[2] + r2[3]) * (1.f / 768.f) + 1e-5f);
  __syncthreads();
  float rstd = rss;
  float dv[3] = {d0, d1, d2};
  #pragma unroll
  for (int i = 0; i < 3; ++i){
    int c = tid + i * 256;
    float vv = dv[i] * rstd * gw[c] + gb[c];
    if (MODE == 1){
      u16 h0, h1; split2h(vv, h0, h1);
      o0[(size_t)tok * LDA2 + c] = h0;
      o0[(size_t)tok * LDA2 + 768 + c] = h1;
    } else {
      size_t idx = (size_t)tok * CC + c;
      of[idx] = vv;
      o0[idx] = f2bf(vv);
    }
  }
}

// ---------------- dense fp16-split NT GEMM: C[M][N] (+)= (1/4096)*A'B' + bias
// A chunks [a0,a0,a1] (colA = k0>=768 ? k0-768 : k0), B chunks [b0,b1,b0]
// (colB = k0<1536 ? k0 : k0-1536). K=2304. M=4096 fixed via grid.
template<int BETA>
__global__ __launch_bounds__(256) void gemm_dense(
    const u16* __restrict__ A, const u16* __restrict__ Bt,
    float* __restrict__ C, const float* __restrict__ bias, int N)
{
  __shared__ u16 As[128 * 32];
  __shared__ u16 Bs[128 * 32];
  int tid = threadIdx.x;
  int lane = tid & 63, wave = tid >> 6;
  int wm = wave & 1, wn = wave >> 1;
  int m0 = blockIdx.y * 128, n0 = blockIdx.x * 128;
  int ra = tid >> 2, ka = (tid & 3) * 8;
  const u16* pa0 = A  + (size_t)(m0 + ra)      * LDA2 + ka;
  const u16* pa1 = A  + (size_t)(m0 + ra + 64) * LDA2 + ka;
  const u16* pb0 = Bt + (size_t)(n0 + ra)      * LDA2 + ka;
  const u16* pb1 = Bt + (size_t)(n0 + ra + 64) * LDA2 + ka;
  floatx4 acc[4][4] = {};
  int el = lane & 15, eq = lane >> 4;
  for (int k0 = 0; k0 < KD; k0 += 32){
    int ca = (k0 >= 768) ? k0 - 768 : k0;
    int cb = (k0 < 1536) ? k0 : k0 - 1536;
    __syncthreads();
    uint4 va0 = *(const uint4*)(pa0 + ca);
    uint4 va1 = *(const uint4*)(pa1 + ca);
    uint4 vb0 = *(const uint4*)(pb0 + cb);
    uint4 vb1 = *(const uint4*)(pb1 + cb);
    *(uint4*)&As[(size_t)ra * 32 + ka]        = va0;
    *(uint4*)&As[(size_t)(ra + 64) * 32 + ka] = va1;
    *(uint4*)&Bs[(size_t)ra * 32 + ka]        = vb0;
    *(uint4*)&Bs[(size_t)(ra + 64) * 32 + ka] = vb1;
    __syncthreads();
    short8 fa[4], fb[4];
    #pragma unroll
    for (int t = 0; t < 4; ++t)
      fa[t] = *(const short8*)&As[(size_t)(wm*64 + t*16 + el) * 32 + eq*8];
    #pragma unroll
    for (int t = 0; t < 4; ++t)
      fb[t] = *(const short8*)&Bs[(size_t)(wn*64 + t*16 + el) * 32 + eq*8];
    #pragma unroll
    for (int mt = 0; mt < 4; ++mt)
      #pragma unroll
      for (int nt = 0; nt < 4; ++nt)
        acc[mt][nt] = __builtin_amdgcn_mfma_f32_16x16x32_f16(fa[mt], fb[nt], acc[mt][nt], 0, 0, 0);
  }
  const float ds = 1.f / 4096.f;
  #pragma unroll
  for (int mt = 0; mt < 4; ++mt){
    #pragma unroll
    for (int nt = 0; nt < 4; ++nt){
      int col = n0 + wn*64 + nt*16 + el;
      float bv = bias ? bias[col] : 0.f;
      #pragma unroll
      for (int r = 0; r < 4; ++r){
        int row = m0 + wm*64 + mt*16 + eq*4 + r;
        size_t idx = (size_t)row * N + col;
        float val = acc[mt][nt][r] * ds + bv;
        if (BETA) val += C[idx];
        C[idx] = val;
      }
    }
  }
}

// ---------------- MFMA flash attention (fp16 3-term split, fp32-class accuracy) ----
// grid (8 qtiles desc, 48 bh), block 256 = 4 waves x 32 rows. K-tile 64.
__global__ __launch_bounds__(256) void flash_mfma(const float* __restrict__ qkv,
    u16* __restrict__ yH)
{
  __shared__ u16 Qs[128 * LDP];
  __shared__ u16 Ks[64 * LDP];
  __shared__ u16 Vt[64 * LDP];
  __shared__ u16 Ps[128 * LDP];
  int tid = threadIdx.x;
  int lane = tid & 63, wv = tid >> 6;
  int qi = 7 - blockIdx.x;              // big tiles dispatch first (LPT)
  int bh = blockIdx.y;
  int b = bh / HH, h = bh % HH;
  int el = lane & 15, eq = lane >> 4;
  int m0 = wv * 32;
  int row0 = qi * 128;

  // stage Q (x64 fp16 2-split): thread -> row tid>>1, dims (tid&1)*32..+31
  {
    int r = tid >> 1, d0 = (tid & 1) * 32;
    const float* src = qkv + (size_t)(b*TT + row0 + r) * C3 + h*HD + d0;
    u16* q0 = &Qs[r * LDP + d0];
    #pragma unroll
    for (int i = 0; i < 32; i += 2){
      u16 a0, a1, b0, b1;
      split2h(src[i], a0, a1);
      split2h(src[i+1], b0, b1);
      *(u32*)&q0[i]      = (u32)a0 | ((u32)b0 << 16);
      *(u32*)&q0[64 + i] = (u32)a1 | ((u32)b1 << 16);
    }
  }
  floatx4 O[2][4] = {};
  float mrow[2][4], lrow[2][4];
  #pragma unroll
  for (int a = 0; a < 2; ++a)
    #pragma unroll
    for (int r = 0; r < 4; ++r){ mrow[a][r] = -1e30f; lrow[a][r] = 0.f; }

  const float cmul = 0.125f * 1.44269504088896340736f / 4096.f; // descale + ln->log2
  const int ABase[6] = {0,32,0,32,64,96};
  const int BBase[6] = {0,32,64,96,0,32};
  int ktmax = 2*qi + 1;

  for (int kt = 0; kt <= ktmax; ++kt){
    __syncthreads();
    { // stage K [key][k0|k1]: thread -> key tid>>2, dims (tid&3)*16..+15
      int j = tid >> 2, d0 = (tid & 3) * 16;
      const float* src = qkv + (size_t)(b*TT + kt*64 + j) * C3 + CC + h*HD + d0;
      u16* kp = &Ks[j * LDP + d0];
      #pragma unroll
      for (int i = 0; i < 16; i += 2){
        u16 a0, a1, b0, b1;
        split2h(src[i], a0, a1);
        split2h(src[i+1], b0, b1);
        *(u32*)&kp[i]      = (u32)a0 | ((u32)b0 << 16);
        *(u32*)&kp[64 + i] = (u32)a1 | ((u32)b1 << 16);
      }
      // stage V transposed [dim][v0|v1]: thread -> dim tid&63, keys (tid>>6)*16..+15
      int d = tid & 63, kp0 = (tid >> 6) * 16;
      const float* vsrc = qkv + (size_t)(b*TT + kt*64 + kp0) * C3 + 2*CC + h*HD + d;
      u16* vt = &Vt[d * LDP];
      #pragma unroll
      for (int i = 0; i < 16; i += 2){
        u16 a0, a1, b0, b1;
        split2h(vsrc[(size_t)i * C3], a0, a1);
        split2h(vsrc[(size_t)(i+1) * C3], b0, b1);
        *(u32*)&vt[kp0 + i]      = (u32)a0 | ((u32)b0 << 16);
        *(u32*)&vt[64 + kp0 + i] = (u32)a1 | ((u32)b1 << 16);
      }
    }
    __syncthreads();
    if (kt*64 > row0 + m0 + 31) continue;   // wave-uniform; barrier counts match
    // S = Q K^T (x4096)
    floatx4 S[2][4] = {};
    #pragma unroll
    for (int ks = 0; ks < 6; ++ks){
      short8 fa[2], fb[4];
      #pragma unroll
      for (int mt = 0; mt < 2; ++mt)
        fa[mt] = *(const short8*)&Qs[(m0 + mt*16 + el) * LDP + ABase[ks] + eq*8];
      #pragma unroll
      for (int nt = 0; nt < 4; ++nt)
        fb[nt] = *(const short8*)&Ks[(nt*16 + el) * LDP + BBase[ks] + eq*8];
      #pragma unroll
      for (int mt = 0; mt < 2; ++mt)
        #pragma unroll
        for (int nt = 0; nt < 4; ++nt)
          S[mt][nt] = __builtin_amdgcn_mfma_f32_16x16x32_f16(fa[mt], fb[nt], S[mt][nt], 0, 0, 0);
    }
    // online softmax (rows wave-private; m row-uniform via shfl, l per-lane partial)
    #pragma unroll
    for (int mt = 0; mt < 2; ++mt){
      #pragma unroll
      for (int nt = 0; nt < 4; ++nt){
        int kcol = kt*64 + nt*16 + el;
        #pragma unroll
        for (int r = 0; r < 4; ++r){
          int grow = row0 + m0 + mt*16 + eq*4 + r;
          float sv = S[mt][nt][r] * cmul;
          S[mt][nt][r] = (kcol <= grow) ? sv : -1e30f;
        }
      }
      #pragma unroll
      for (int r = 0; r < 4; ++r){
        float tmax = fmaxf(fmaxf(S[mt][0][r], S[mt][1][r]), fmaxf(S[mt][2][r], S[mt][3][r]));
        #pragma unroll
        for (int off = 1; off < 16; off <<= 1) tmax = fmaxf(tmax, __shfl_xor(tmax, off));
        float mnew = fmaxf(mrow[mt][r], tmax);
        float al = exp2f(mrow[mt][r] - mnew);
        mrow[mt][r] = mnew;
        lrow[mt][r] *= al;
        #pragma unroll
        for (int nt = 0; nt < 4; ++nt) O[mt][nt][r] *= al;
        #pragma unroll
        for (int nt = 0; nt < 4; ++nt){
          float p = exp2f(S[mt][nt][r] - mnew);
          lrow[mt][r] += p;
          S[mt][nt][r] = p;
        }
      }
      // write P (x64, 2-split) into wave-private Ps rows
      #pragma unroll
      for (int nt = 0; nt < 4; ++nt){
        #pragma unroll
        for (int r = 0; r < 4; ++r){
          u16 p0, p1; split2h(S[mt][nt][r], p0, p1);
          int rowl = m0 + mt*16 + eq*4 + r;
          Ps[rowl * LDP + nt*16 + el] = p0;
          Ps[rowl * LDP + 64 + nt*16 + el] = p1;
        }
      }
    }
    // O += P V (P x64, V x64)
    #pragma unroll
    for (int ks = 0; ks < 6; ++ks){
      short8 fa[2], fb[4];
      #pragma unroll
      for (int mt = 0; mt < 2; ++mt)
        fa[mt] = *(const short8*)&Ps[(m0 + mt*16 + el) * LDP + ABase[ks] + eq*8];
      #pragma unroll
      for (int nt = 0; nt < 4; ++nt)
        fb[nt] = *(const short8*)&Vt[(nt*16 + el) * LDP + BBase[ks] + eq*8];
      #pragma unroll
      for (int mt = 0; mt < 2; ++mt)
        #pragma unroll
        for (int nt = 0; nt < 4; ++nt)
          O[mt][nt] = __builtin_amdgcn_mfma_f32_16x16x32_f16(fa[mt], fb[nt], O[mt][nt], 0, 0, 0);
    }
  }
  // epilogue: reduce l over el lanes, normalize (O is x4096), write yH 2-split
  #pragma unroll
  for (int mt = 0; mt < 2; ++mt){
    #pragma unroll
    for (int r = 0; r < 4; ++r){
      float l = lrow[mt][r];
      #pragma unroll
      for (int off = 1; off < 16; off <<= 1) l += __shfl_xor(l, off);
      float inv = 1.f / (l * 4096.f);
      int grow = row0 + m0 + mt*16 + eq*4 + r;
      u16* dst = yH + (size_t)(b*TT + grow) * LDA2 + h*HD;
      #pragma unroll
      for (int nt = 0; nt < 4; ++nt){
        float yv = O[mt][nt][r] * inv;
        u16 y0, y1; split2h(yv, y0, y1);
        dst[nt*16 + el] = y0;
        dst[768 + nt*16 + el] = y1;
      }
    }
  }
}

// ---------------- router: fp32 logits, softmax, top-2 ----------------
__global__ __launch_bounds__(256) void router_kernel(const float* __restrict__ xn2,
    const float* __restrict__ Wr, int* __restrict__ eids, float* __restrict__ wts)
{
  int wave = threadIdx.x >> 6, lane = threadIdx.x & 63;
  int tok = blockIdx.x * 4 + wave;
  int g = lane >> 4, e = lane & 15;
  const float* xr = xn2 + (size_t)tok * CC;
  float s = 0.f;
  for (int c4 = 0; c4 < 192; ++c4){
    int c = c4 * 4 + g;
    s += xr[c] * Wr[c * EE + e];
  }
  s += __shfl_xor(s, 16);
  s += __shfl_xor(s, 32);
  float mx = s;
  #pragma unroll
  for (int off = 1; off < 16; off <<= 1) mx = fmaxf(mx, __shfl_xor(mx, off));
  float p = expf(s - mx);
  float Z = p;
  #pragma unroll
  for (int off = 1; off < 16; off <<= 1) Z += __shfl_xor(Z, off);
  p /= Z;
  float best = -1.f; int bi = 0;
  for (int ee = 0; ee < 16; ++ee){
    float pe = __shfl(p, ee);
    if (pe > best){ best = pe; bi = ee; }
  }
  float sec = -1.f; int si = 0;
  for (int ee = 0; ee < 16; ++ee){
    float pe = __shfl(p, ee);
    if (ee != bi && pe > sec){ sec = pe; si = ee; }
  }
  if (lane == 0){
    eids[tok*2] = bi;  eids[tok*2+1] = si;
    wts [tok*2] = best; wts[tok*2+1] = sec;
  }
}

__global__ __launch_bounds__(256) void moe_count(const int* __restrict__ eids,
    int* __restrict__ counts, int* __restrict__ offs, int* __restrict__ curs)
{
  __shared__ int lc[EE];
  int tid = threadIdx.x;
  if (tid < EE) lc[tid] = 0;
  __syncthreads();
  for (int i = tid; i < NSLOT; i += 256) atomicAdd(&lc[eids[i]], 1);
  __syncthreads();
  if (tid == 0){
    int run = 0;
    for (int e = 0; e < EE; ++e){
      counts[e] = lc[e]; offs[e] = run; curs[e] = run; run += lc[e];
    }
    offs[EE] = run;
  }
}

__global__ __launch_bounds__(256) void moe_scatter(const int* __restrict__ eids,
    const float* __restrict__ wts, int* __restrict__ curs,
    int* __restrict__ rowmap, float* __restrict__ wgtm)
{
  int i = blockIdx.x * 256 + threadIdx.x;
  int e = eids[i];
  int pos = atomicAdd(&curs[e], 1);
  rowmap[pos] = i >> 1;
  wgtm[pos] = wts[i];
}

__global__ __launch_bounds__(256) void add2(const float* __restrict__ a,
    const float* __restrict__ b, float* __restrict__ o, int n)
{
  int i = blockIdx.x * 256 + threadIdx.x;
  if (i < n) o[i] = a[i] + b[i];
}

// ---------------- MoE expert GEMM1: H = gelu(gather(xn2b) @ W1t^T + b1) --------------
__global__ __launch_bounds__(256) void gemm_moe1(
    const u16* __restrict__ Xb, const u16* __restrict__ W1t, const float* __restrict__ b1,
    u16* __restrict__ H, const int* __restrict__ counts, const int* __restrict__ offs,
    const int* __restrict__ rowmap)
{
  int e = blockIdx.z;
  int cnt = counts[e];
  int m0 = blockIdx.y * 128;
  if (m0 >= cnt) return;
  int off = offs[e];
  int n0 = blockIdx.x * 128;
  const u16* Bt = W1t + (size_t)e * DFFN * CC;
  __shared__ u16 As[128 * 32];
  __shared__ u16 Bs[128 * 32];
  int tid = threadIdx.x;
  int lane = tid & 63, wave = tid >> 6;
  int wm = wave & 1, wn = wave >> 1;
  int ra = tid >> 2, ka = (tid & 3) * 8;
  int r0 = m0 + ra, r1i = m0 + ra + 64;
  const u16* pa0 = (r0  < cnt) ? Xb + (size_t)rowmap[off + r0]  * CC + ka : nullptr;
  const u16* pa1 = (r1i < cnt) ? Xb + (size_t)rowmap[off + r1i] * CC + ka : nullptr;
  const u16* pb0 = Bt + (size_t)(n0 + ra)      * CC + ka;
  const u16* pb1 = Bt + (size_t)(n0 + ra + 64) * CC + ka;
  floatx4 acc[4][4] = {};
  int el = lane & 15, eq = lane >> 4;
  uint4 z4 = {0u, 0u, 0u, 0u};
  for (int k0 = 0; k0 < CC; k0 += 32){
    __syncthreads();
    uint4 va0 = pa0 ? *(const uint4*)(pa0 + k0) : z4;
    uint4 va1 = pa1 ? *(const uint4*)(pa1 + k0) : z4;
    uint4 vb0 = *(const uint4*)(pb0 + k0);
    uint4 vb1 = *(const uint4*)(pb1 + k0);
    *(uint4*)&As[(size_t)ra * 32 + ka]        = va0;
    *(uint4*)&As[(size_t)(ra + 64) * 32 + ka] = va1;
    *(uint4*)&Bs[(size_t)ra * 32 + ka]        = vb0;
    *(uint4*)&Bs[(size_t)(ra + 64) * 32 + ka] = vb1;
    __syncthreads();
    short8 fa[4], fb[4];
    #pragma unroll
    for (int t = 0; t < 4; ++t)
      fa[t] = *(const short8*)&As[(size_t)(wm*64 + t*16 + el) * 32 + eq*8];
    #pragma unroll
    for (int t = 0; t < 4; ++t)
      fb[t] = *(const short8*)&Bs[(size_t)(wn*64 + t*16 + el) * 32 + eq*8];
    #pragma unroll
    for (int mt = 0; mt < 4; ++mt)
      #pragma unroll
      for (int nt = 0; nt < 4; ++nt)
        acc[mt][nt] = __builtin_amdgcn_mfma_f32_16x16x32_bf16(fa[mt], fb[nt], acc[mt][nt], 0, 0, 0);
  }
  #pragma unroll
  for (int mt = 0; mt < 4; ++mt){
    #pragma unroll
    for (int nt = 0; nt < 4; ++nt){
      int col = n0 + wn*64 + nt*16 + el;
      float bv = b1[(size_t)e * DFFN + col];
      #pragma unroll
      for (int r = 0; r < 4; ++r){
        int row = m0 + wm*64 + mt*16 + eq*4 + r;
        if (row < cnt)
          H[(size_t)(off + row) * DFFN + col] = f2bf(gelu_exact(acc[mt][nt][r] + bv));
      }
    }
  }
}

// ---------------- MoE expert GEMM2: out[tok] += w * (H @ W2t^T + b2) ----------------
__global__ __launch_bounds__(256) void gemm_moe2(
    const u16* __restrict__ H, const u16* __restrict__ W2t, const float* __restrict__ b2,
    float* __restrict__ Out, const int* __restrict__ counts, const int* __restrict__ offs,
    const int* __restrict__ rowmap, const float* __restrict__ wgtm)
{
  int e = blockIdx.z;
  int cnt = counts[e];
  int m0 = blockIdx.y * 128;
  if (m0 >= cnt) return;
  int off = offs[e];
  int n0 = blockIdx.x * 128;
  const u16* Bt = W2t + (size_t)e * CC * DFFN;
  __shared__ u16 As[128 * 32];
  __shared__ u16 Bs[128 * 32];
  int tid = threadIdx.x;
  int lane = tid & 63, wave = tid >> 6;
  int wm = wave & 1, wn = wave >> 1;
  int ra = tid >> 2, ka = (tid & 3) * 8;
  int r0 = m0 + ra, r1i = m0 + ra + 64;
  const u16* pa0 = (r0  < cnt) ? H + (size_t)(off + r0)  * DFFN + ka : nullptr;
  const u16* pa1 = (r1i < cnt) ? H + (size_t)(off + r1i) * DFFN + ka : nullptr;
  const u16* pb0 = Bt + (size_t)(n0 + ra)      * DFFN + ka;
  const u16* pb1 = Bt + (size_t)(n0 + ra + 64) * DFFN + ka;
  floatx4 acc[4][4] = {};
  int el = lane & 15, eq = lane >> 4;
  uint4 z4 = {0u, 0u, 0u, 0u};
  for (int k0 = 0; k0 < DFFN; k0 += 32){
    __syncthreads();
    uint4 va0 = pa0 ? *(const uint4*)(pa0 + k0) : z4;
    uint4 va1 = pa1 ? *(const uint4*)(pa1 + k0) : z4;
    uint4 vb0 = *(const uint4*)(pb0 + k0);
    uint4 vb1 = *(const uint4*)(pb1 + k0);
    *(uint4*)&As[(size_t)ra * 32 + ka]        = va0;
    *(uint4*)&As[(size_t)(ra + 64) * 32 + ka] = va1;
    *(uint4*)&Bs[(size_t)ra * 32 + ka]        = vb0;
    *(uint4*)&Bs[(size_t)(ra + 64) * 32 + ka] = vb1;
    __syncthreads();
    short8 fa[4], fb[4];
    #pragma unroll
    for (int t = 0; t < 4; ++t)
      fa[t] = *(const short8*)&As[(size_t)(wm*64 + t*16 + el) * 32 + eq*8];
    #pragma unroll
    for (int t = 0; t < 4; ++t)
      fb[t] = *(const short8*)&Bs[(size_t)(wn*64 + t*16 + el) * 32 + eq*8];
    #pragma unroll
    for (int mt = 0; mt < 4; ++mt)
      #pragma unroll
      for (int nt = 0; nt < 4; ++nt)
        acc[mt][nt] = __builtin_amdgcn_mfma_f32_16x16x32_bf16(fa[mt], fb[nt], acc[mt][nt], 0, 0, 0);
  }
  #pragma unroll
  for (int mt = 0; mt < 4; ++mt){
    #pragma unroll
    for (int nt = 0; nt < 4; ++nt){
      int col = n0 + wn*64 + nt*16 + el;
      float bv = b2[(size_t)e * CC + col];
      #pragma unroll
      for (int r = 0; r < 4; ++r){
        int row = m0 + wm*64 + mt*16 + eq*4 + r;
        if (row < cnt){
          int slot = off + row;
          int tok = rowmap[slot];
          float wv = wgtm[slot];
          atomicAdd(&Out[(size_t)tok * CC + col], wv * (acc[mt][nt][r] + bv));
        }
      }
    }
  }
}

// =====================================================================================
extern "C" void kernel_launch(void* const* d_in, const int* in_sizes, int n_in,
                              void* d_out, int out_size, void* d_ws, size_t ws_size,
                              hipStream_t stream)
{
  const float* x     = (const float*)d_in[0];
  const float* ln1w  = (const float*)d_in[1];
  const float* ln1b  = (const float*)d_in[2];
  const float* Wattn = (const float*)d_in[3];
  const float* battn = (const float*)d_in[4];
  const float* Wproj = (const float*)d_in[5];
  const float* bproj = (const float*)d_in[6];
  const float* ln2w  = (const float*)d_in[7];
  const float* ln2b  = (const float*)d_in[8];
  const float* Wrout = (const float*)d_in[9];
  const float* W1    = (const float*)d_in[10];
  const float* b1    = (const float*)d_in[11];
  const float* W2    = (const float*)d_in[12];
  const float* b2    = (const float*)d_in[13];
  float* out = (float*)d_out;

  char* w = (char*)d_ws;
  auto alloc = [&](size_t bytes)->char* {
    char* p = w; w += (bytes + 255) & ~(size_t)255; return p;
  };
  u16* watp  = (u16*)alloc((size_t)C3 * LDA2 * 2);      //  7.1 MB  fp16 2-split [N][1536]
  u16* wptp  = (u16*)alloc((size_t)CC * LDA2 * 2);      //  2.4 MB
  u16* w1t   = (u16*)alloc((size_t)EE * DFFN * CC * 2); // 75.5 MB  bf16
  u16* w2t   = (u16*)alloc((size_t)EE * CC * DFFN * 2); // 75.5 MB
  u16* xH    = (u16*)alloc((size_t)NTOK * LDA2 * 2);    // 12.6 MB  LN1 out, fp16 2-split
  float* qkv = (float*)alloc((size_t)NTOK * C3 * 4);    // 37.7 MB
  u16* yH    = (u16*)alloc((size_t)NTOK * LDA2 * 2);    // 12.6 MB  attn out, fp16 2-split
  u16* Hbuf  = (u16*)alloc((size_t)NSLOT * DFFN * 2);   // 50.3 MB
  float* x2    = (float*)alloc((size_t)NTOK * CC * 4);
  float* xn2   = (float*)alloc((size_t)NTOK * CC * 4);
  u16*   xn2b  = (u16*)alloc((size_t)NTOK * CC * 2);
  int*   eids  = (int*)alloc(NSLOT * 4);
  float* wts   = (float*)alloc(NSLOT * 4);
  int* counts  = (int*)alloc(256);
  int* offs    = (int*)alloc(256);
  int* curs    = (int*)alloc(256);
  int* rowmap  = (int*)alloc(NSLOT * 4);
  float* wgtm  = (float*)alloc(NSLOT * 4);

  // 1) weight conversion
  hipLaunchKernelGGL((transpose_split<1>), dim3(C3/32, CC/32, 1), dim3(256), 0, stream,
                     Wattn, watp, CC, C3);
  hipLaunchKernelGGL((transpose_split<1>), dim3(CC/32, CC/32, 1), dim3(256), 0, stream,
                     Wproj, wptp, CC, CC);
  hipLaunchKernelGGL((transpose_split<0>), dim3(DFFN/32, CC/32, EE), dim3(256), 0, stream,
                     W1, w1t, CC, DFFN);
  hipLaunchKernelGGL((transpose_split<0>), dim3(CC/32, DFFN/32, EE), dim3(256), 0, stream,
                     W2, w2t, DFFN, CC);
  // 2) LN1 -> fp16 2-split xH
  hipLaunchKernelGGL((ln_kernel<1>), dim3(NTOK), dim3(256), 0, stream,
                     x, ln1w, ln1b, (float*)nullptr, xH);
  // 3) qkv = xn @ W_attn + b_attn (single K=2304 fp16 3-term pass)
  hipLaunchKernelGGL((gemm_dense<0>), dim3(C3/128, NTOK/128), dim3(256), 0, stream,
                     xH, watp, qkv, battn, C3);
  // 4) MFMA flash attention -> yH (fp16 2-split)
  hipLaunchKernelGGL(flash_mfma, dim3(8, BB*HH), dim3(256), 0, stream, qkv, yH);
  // 5) x2 = x + y @ W_proj + b_proj
  hipMemcpyAsync(x2, x, (size_t)NTOK * CC * 4, hipMemcpyDeviceToDevice, stream);
  hipLaunchKernelGGL((gemm_dense<1>), dim3(CC/128, NTOK/128), dim3(256), 0, stream,
                     yH, wptp, x2, bproj, CC);
  // 6) LN2 -> xn2 fp32 (router) + bf16 (MoE input)
  hipLaunchKernelGGL((ln_kernel<0>), dim3(NTOK), dim3(256), 0, stream,
                     x2, ln2w, ln2b, xn2, xn2b);
  // 7) router + expert gather lists
  hipLaunchKernelGGL(router_kernel, dim3(NTOK/4), dim3(256), 0, stream, xn2, Wrout, eids, wts);
  hipLaunchKernelGGL(moe_count, dim3(1), dim3(256), 0, stream, eids, counts, offs, curs);
  hipLaunchKernelGGL(moe_scatter, dim3(NSLOT/256), dim3(256), 0, stream, eids, wts, curs, rowmap, wgtm);
  // 8) out = x2 + xn2
  hipLaunchKernelGGL(add2, dim3(NTOK*CC/256), dim3(256), 0, stream, x2, xn2, out, NTOK*CC);
  // 9) MoE expert FFN
  hipLaunchKernelGGL(gemm_moe1, dim3(DFFN/128, 32, EE), dim3(256), 0, stream,
                     xn2b, w1t, b1, Hbuf, counts, offs, rowmap);
  hipLaunchKernelGGL(gemm_moe2, dim3(CC/128, 32, EE), dim3(256), 0, stream,
                     Hbuf, w2t, b2, out, counts, offs, rowmap, wgtm);
}

// Round 4
// 948.304 us; speedup vs baseline: 1.7312x; 1.0749x over previous
//
#include <hip/hip_runtime.h>
#include <math.h>

#define CC    768
#define C3    2304
#define KD    2304   /* dense GEMM K: 3 chunks x 768 (fp16 3-term split) */
#define LDA2  1536   /* compact 2-split row stride: [a0(768) | a1(768)] */
#define TT    1024
#define BB    4
#define HH    12
#define HD    64
#define EE    16
#define DFFN  3072
#define NTOK  4096
#define NSLOT 8192
#define LDP   136    /* flash LDS padded stride (halves) */

typedef unsigned short u16;
typedef unsigned int   u32;
typedef __attribute__((ext_vector_type(8))) short short8;
typedef __attribute__((ext_vector_type(4))) float floatx4;

__device__ __forceinline__ u16 f2bf(float f){
  u32 x = __builtin_bit_cast(u32, f);
  x += 0x7fffu + ((x >> 16) & 1u);   // RNE
  return (u16)(x >> 16);
}
__device__ __forceinline__ u16 f2h(float f){
  _Float16 h = (_Float16)f;
  return __builtin_bit_cast(u16, h);
}
__device__ __forceinline__ float h2f(u16 u){
  return (float)__builtin_bit_cast(_Float16, u);
}
__device__ __forceinline__ float gelu_exact(float v){
  return 0.5f * v * (1.f + erff(v * 0.70710678118654752440f));
}
// x64-scaled fp16 2-way split: v*64 = h0 + h1 (+ <2^-24 rel residual)
__device__ __forceinline__ void split2h(float v, u16& h0, u16& h1){
  float vs = v * 64.f;
  h0 = f2h(vs);
  h1 = f2h(vs - h2f(h0));
}
// async global->LDS, 16B per lane, LDS dest = wave-uniform base + lane*16
__device__ __forceinline__ void gload_lds16(const void* g, void* l){
  __builtin_amdgcn_global_load_lds(
      (const __attribute__((address_space(1))) void*)g,
      (__attribute__((address_space(3))) void*)l, 16, 0, 0);
}

// ---------------- fp32 -> transpose. MODE 0: plain bf16 [z][Cn][R].
// MODE 1: fp16 2-split x64 [Cn][1536] ([b0|b1])
template<int MODE>
__global__ __launch_bounds__(256) void transpose_split(const float* __restrict__ src,
    u16* __restrict__ d0, int R, int Cn)
{
  __shared__ float tile[32][33];
  int z = blockIdx.z;
  const float* s = src + (size_t)z * R * Cn;
  int c0 = blockIdx.x * 32, r0 = blockIdx.y * 32;
  int tx = threadIdx.x & 31, ty = threadIdx.x >> 5;
  #pragma unroll
  for (int j = 0; j < 4; ++j)
    tile[ty + j*8][tx] = s[(size_t)(r0 + ty + j*8) * Cn + c0 + tx];
  __syncthreads();
  #pragma unroll
  for (int j = 0; j < 4; ++j){
    float v = tile[tx][ty + j*8];
    if (MODE == 1){
      u16 h0, h1; split2h(v, h0, h1);
      size_t base = (size_t)(c0 + ty + j*8) * LDA2 + (r0 + tx);
      d0[base] = h0; d0[base + 768] = h1;
    } else {
      d0[(size_t)z * R * Cn + (size_t)(c0 + ty + j*8) * R + r0 + tx] = f2bf(v);
    }
  }
}

// ---------------- LayerNorm. MODE 0: fp32 out + bf16 out (stride CC).
// MODE 1: fp16 2-split x64 out [tok][1536].
template<int MODE>
__global__ __launch_bounds__(256) void ln_kernel(const float* __restrict__ x,
    const float* __restrict__ gw, const float* __restrict__ gb,
    float* __restrict__ of, u16* __restrict__ o0)
{
  int tok = blockIdx.x, tid = threadIdx.x;
  const float* xr = x + (size_t)tok * CC;
  float v0 = xr[tid], v1 = xr[tid + 256], v2 = xr[tid + 512];
  __shared__ float r1[4], r2[4];
  __shared__ float mus, rss;
  float s = v0 + v1 + v2;
  #pragma unroll
  for (int off = 32; off >= 1; off >>= 1) s += __shfl_down(s, off);
  if ((tid & 63) == 0) r1[tid >> 6] = s;
  __syncthreads();
  if (tid == 0) mus = (r1[0] + r1[1] + r1[2] + r1[3]) * (1.f / 768.f);
  __syncthreads();
  float mu = mus;
  float d0 = v0 - mu, d1 = v1 - mu, d2 = v2 - mu;
  float t = d0*d0 + d1*d1 + d2*d2;
  #pragma unroll
  for (int off = 32; off >= 1; off >>= 1) t += __shfl_down(t, off);
  if ((tid & 63) == 0) r2[tid >> 6] = t;
  __syncthreads();
  if (tid == 0) rss = rsqrtf((r2[0] + r2[1] + r2[2] + r2[3]) * (1.f / 768.f) + 1e-5f);
  __syncthreads();
  float rstd = rss;
  float dv[3] = {d0, d1, d2};
  #pragma unroll
  for (int i = 0; i < 3; ++i){
    int c = tid + i * 256;
    float vv = dv[i] * rstd * gw[c] + gb[c];
    if (MODE == 1){
      u16 h0, h1; split2h(vv, h0, h1);
      o0[(size_t)tok * LDA2 + c] = h0;
      o0[(size_t)tok * LDA2 + 768 + c] = h1;
    } else {
      size_t idx = (size_t)tok * CC + c;
      of[idx] = vv;
      o0[idx] = f2bf(vv);
    }
  }
}

// ---------------- dense fp16-split NT GEMM: C[M][N] = (1/4096)*A'B' + bias + resid
// A chunks [a0,a0,a1], B chunks [b0,b1,b0]. K=2304. async LDS staging.
__global__ __launch_bounds__(256) void gemm_dense(
    const u16* __restrict__ A, const u16* __restrict__ Bt,
    float* __restrict__ C, const float* __restrict__ bias,
    const float* __restrict__ resid, int N)
{
  __shared__ u16 As[128 * 32];
  __shared__ u16 Bs[128 * 32];
  int tid = threadIdx.x;
  int lane = tid & 63, wave = tid >> 6;
  int wm = wave & 1, wn = wave >> 1;
  int m0 = blockIdx.y * 128, n0 = blockIdx.x * 128;
  int ra = tid >> 2, ka = (tid & 3) * 8;
  const u16* pa0 = A  + (size_t)(m0 + ra)      * LDA2 + ka;
  const u16* pa1 = A  + (size_t)(m0 + ra + 64) * LDA2 + ka;
  const u16* pb0 = Bt + (size_t)(n0 + ra)      * LDA2 + ka;
  const u16* pb1 = Bt + (size_t)(n0 + ra + 64) * LDA2 + ka;
  u16* lA0 = As + wave*512;        u16* lA1 = As + 2048 + wave*512;
  u16* lB0 = Bs + wave*512;        u16* lB1 = Bs + 2048 + wave*512;
  floatx4 acc[4][4] = {};
  int el = lane & 15, eq = lane >> 4;
  for (int k0 = 0; k0 < KD; k0 += 32){
    int ca = (k0 >= 768) ? k0 - 768 : k0;
    int cb = (k0 < 1536) ? k0 : k0 - 1536;
    __syncthreads();
    gload_lds16(pa0 + ca, lA0);
    gload_lds16(pa1 + ca, lA1);
    gload_lds16(pb0 + cb, lB0);
    gload_lds16(pb1 + cb, lB1);
    __syncthreads();
    short8 fa[4], fb[4];
    #pragma unroll
    for (int t = 0; t < 4; ++t)
      fa[t] = *(const short8*)&As[(size_t)(wm*64 + t*16 + el) * 32 + eq*8];
    #pragma unroll
    for (int t = 0; t < 4; ++t)
      fb[t] = *(const short8*)&Bs[(size_t)(wn*64 + t*16 + el) * 32 + eq*8];
    #pragma unroll
    for (int mt = 0; mt < 4; ++mt)
      #pragma unroll
      for (int nt = 0; nt < 4; ++nt)
        acc[mt][nt] = __builtin_amdgcn_mfma_f32_16x16x32_f16(fa[mt], fb[nt], acc[mt][nt], 0, 0, 0);
  }
  const float ds = 1.f / 4096.f;
  #pragma unroll
  for (int mt = 0; mt < 4; ++mt){
    #pragma unroll
    for (int nt = 0; nt < 4; ++nt){
      int col = n0 + wn*64 + nt*16 + el;
      float bv = bias ? bias[col] : 0.f;
      #pragma unroll
      for (int r = 0; r < 4; ++r){
        int row = m0 + wm*64 + mt*16 + eq*4 + r;
        size_t idx = (size_t)row * N + col;
        float val = acc[mt][nt][r] * ds + bv;
        if (resid) val += resid[idx];
        C[idx] = val;
      }
    }
  }
}

// ---------------- MFMA flash attention (fp16 3-term split, fp32-class accuracy) ----
// grid (16 qtiles LPT, 48 bh), block 256 = 4 waves x 16 rows. Q-tile 64, K-tile 64.
// LDS 69.6 KB -> 2 blocks/CU.
__global__ __launch_bounds__(256) void flash_mfma(const float* __restrict__ qkv,
    u16* __restrict__ yH)
{
  __shared__ u16 Qs[64 * LDP];
  __shared__ u16 Ks[64 * LDP];
  __shared__ u16 Vt[64 * LDP];
  __shared__ u16 Ps[64 * LDP];
  int tid = threadIdx.x;
  int lane = tid & 63, wv = tid >> 6;
  int qi = 15 - blockIdx.x;              // big tiles dispatch first (LPT)
  int bh = blockIdx.y;
  int b = bh / HH, h = bh % HH;
  int el = lane & 15, eq = lane >> 4;
  int m0 = wv * 16;
  int row0 = qi * 64;

  // stage Q (x64 fp16 2-split): thread -> row tid>>2 (wave-private rows!)
  {
    int r = tid >> 2, d0 = (tid & 3) * 16;
    const float* src = qkv + (size_t)(b*TT + row0 + r) * C3 + h*HD + d0;
    u16* q0 = &Qs[r * LDP + d0];
    #pragma unroll
    for (int i = 0; i < 16; i += 2){
      u16 a0, a1, b0, b1;
      split2h(src[i], a0, a1);
      split2h(src[i+1], b0, b1);
      *(u32*)&q0[i]      = (u32)a0 | ((u32)b0 << 16);
      *(u32*)&q0[64 + i] = (u32)a1 | ((u32)b1 << 16);
    }
  }
  floatx4 O[4] = {};
  float mrow[4], lrow[4];
  #pragma unroll
  for (int r = 0; r < 4; ++r){ mrow[r] = -1e30f; lrow[r] = 0.f; }

  const float cmul = 0.125f * 1.44269504088896340736f / 4096.f; // descale + ln->log2
  const int ABase[6] = {0,32,0,32,64,96};
  const int BBase[6] = {0,32,64,96,0,32};

  for (int kt = 0; kt <= qi; ++kt){
    __syncthreads();
    { // stage K [key][k0|k1]: thread -> key tid>>2, dims (tid&3)*16..+15
      int j = tid >> 2, d0 = (tid & 3) * 16;
      const float* src = qkv + (size_t)(b*TT + kt*64 + j) * C3 + CC + h*HD + d0;
      u16* kp = &Ks[j * LDP + d0];
      #pragma unroll
      for (int i = 0; i < 16; i += 2){
        u16 a0, a1, b0, b1;
        split2h(src[i], a0, a1);
        split2h(src[i+1], b0, b1);
        *(u32*)&kp[i]      = (u32)a0 | ((u32)b0 << 16);
        *(u32*)&kp[64 + i] = (u32)a1 | ((u32)b1 << 16);
      }
      // stage V transposed [dim][v0|v1]: thread -> dim tid&63, keys (tid>>6)*16..+15
      int d = tid & 63, kp0 = (tid >> 6) * 16;
      const float* vsrc = qkv + (size_t)(b*TT + kt*64 + kp0) * C3 + 2*CC + h*HD + d;
      u16* vt = &Vt[d * LDP];
      #pragma unroll
      for (int i = 0; i < 16; i += 2){
        u16 a0, a1, b0, b1;
        split2h(vsrc[(size_t)i * C3], a0, a1);
        split2h(vsrc[(size_t)(i+1) * C3], b0, b1);
        *(u32*)&vt[kp0 + i]      = (u32)a0 | ((u32)b0 << 16);
        *(u32*)&vt[64 + kp0 + i] = (u32)a1 | ((u32)b1 << 16);
      }
    }
    __syncthreads();
    // S = Q K^T (x4096)
    floatx4 S[4] = {};
    #pragma unroll
    for (int ks = 0; ks < 6; ++ks){
      short8 fa = *(const short8*)&Qs[(m0 + el) * LDP + ABase[ks] + eq*8];
      short8 fb[4];
      #pragma unroll
      for (int nt = 0; nt < 4; ++nt)
        fb[nt] = *(const short8*)&Ks[(nt*16 + el) * LDP + BBase[ks] + eq*8];
      #pragma unroll
      for (int nt = 0; nt < 4; ++nt)
        S[nt] = __builtin_amdgcn_mfma_f32_16x16x32_f16(fa, fb[nt], S[nt], 0, 0, 0);
    }
    // mask + online softmax (16 rows per wave; m row-uniform via shfl over el)
    #pragma unroll
    for (int nt = 0; nt < 4; ++nt){
      int kcol = kt*64 + nt*16 + el;
      #pragma unroll
      for (int r = 0; r < 4; ++r){
        int grow = row0 + m0 + eq*4 + r;
        float sv = S[nt][r] * cmul;
        S[nt][r] = (kcol <= grow) ? sv : -1e30f;
      }
    }
    #pragma unroll
    for (int r = 0; r < 4; ++r){
      float tmax = fmaxf(fmaxf(S[0][r], S[1][r]), fmaxf(S[2][r], S[3][r]));
      #pragma unroll
      for (int off = 1; off < 16; off <<= 1) tmax = fmaxf(tmax, __shfl_xor(tmax, off));
      float mnew = fmaxf(mrow[r], tmax);
      float al = exp2f(mrow[r] - mnew);
      mrow[r] = mnew;
      lrow[r] *= al;
      #pragma unroll
      for (int nt = 0; nt < 4; ++nt) O[nt][r] *= al;
      #pragma unroll
      for (int nt = 0; nt < 4; ++nt){
        float p = exp2f(S[nt][r] - mnew);
        lrow[r] += p;
        S[nt][r] = p;
      }
    }
    // write P (x64, 2-split) into wave-private Ps rows
    #pragma unroll
    for (int nt = 0; nt < 4; ++nt){
      #pragma unroll
      for (int r = 0; r < 4; ++r){
        u16 p0, p1; split2h(S[nt][r], p0, p1);
        int rowl = m0 + eq*4 + r;
        Ps[rowl * LDP + nt*16 + el] = p0;
        Ps[rowl * LDP + 64 + nt*16 + el] = p1;
      }
    }
    // O += P V (P x64, V x64)
    #pragma unroll
    for (int ks = 0; ks < 6; ++ks){
      short8 fa = *(const short8*)&Ps[(m0 + el) * LDP + ABase[ks] + eq*8];
      short8 fb[4];
      #pragma unroll
      for (int nt = 0; nt < 4; ++nt)
        fb[nt] = *(const short8*)&Vt[(nt*16 + el) * LDP + BBase[ks] + eq*8];
      #pragma unroll
      for (int nt = 0; nt < 4; ++nt)
        O[nt] = __builtin_amdgcn_mfma_f32_16x16x32_f16(fa, fb[nt], O[nt], 0, 0, 0);
    }
  }
  // epilogue: reduce l over el lanes, normalize (O is x4096), write yH 2-split
  #pragma unroll
  for (int r = 0; r < 4; ++r){
    float l = lrow[r];
    #pragma unroll
    for (int off = 1; off < 16; off <<= 1) l += __shfl_xor(l, off);
    float inv = 1.f / (l * 4096.f);
    int grow = row0 + m0 + eq*4 + r;
    u16* dst = yH + (size_t)(b*TT + grow) * LDA2 + h*HD;
    #pragma unroll
    for (int nt = 0; nt < 4; ++nt){
      float yv = O[nt][r] * inv;
      u16 y0, y1; split2h(yv, y0, y1);
      dst[nt*16 + el] = y0;
      dst[768 + nt*16 + el] = y1;
    }
  }
}

// ---------------- router: fp32 logits, softmax, top-2 ----------------
__global__ __launch_bounds__(256) void router_kernel(const float* __restrict__ xn2,
    const float* __restrict__ Wr, int* __restrict__ eids, float* __restrict__ wts)
{
  int wave = threadIdx.x >> 6, lane = threadIdx.x & 63;
  int tok = blockIdx.x * 4 + wave;
  int g = lane >> 4, e = lane & 15;
  const float* xr = xn2 + (size_t)tok * CC;
  float s = 0.f;
  for (int c4 = 0; c4 < 192; ++c4){
    int c = c4 * 4 + g;
    s += xr[c] * Wr[c * EE + e];
  }
  s += __shfl_xor(s, 16);
  s += __shfl_xor(s, 32);
  float mx = s;
  #pragma unroll
  for (int off = 1; off < 16; off <<= 1) mx = fmaxf(mx, __shfl_xor(mx, off));
  float p = expf(s - mx);
  float Z = p;
  #pragma unroll
  for (int off = 1; off < 16; off <<= 1) Z += __shfl_xor(Z, off);
  p /= Z;
  float best = -1.f; int bi = 0;
  for (int ee = 0; ee < 16; ++ee){
    float pe = __shfl(p, ee);
    if (pe > best){ best = pe; bi = ee; }
  }
  float sec = -1.f; int si = 0;
  for (int ee = 0; ee < 16; ++ee){
    float pe = __shfl(p, ee);
    if (ee != bi && pe > sec){ sec = pe; si = ee; }
  }
  if (lane == 0){
    eids[tok*2] = bi;  eids[tok*2+1] = si;
    wts [tok*2] = best; wts[tok*2+1] = sec;
  }
}

__global__ __launch_bounds__(256) void moe_count(const int* __restrict__ eids,
    int* __restrict__ counts, int* __restrict__ offs, int* __restrict__ curs)
{
  __shared__ int lc[EE];
  int tid = threadIdx.x;
  if (tid < EE) lc[tid] = 0;
  __syncthreads();
  for (int i = tid; i < NSLOT; i += 256) atomicAdd(&lc[eids[i]], 1);
  __syncthreads();
  if (tid == 0){
    int run = 0;
    for (int e = 0; e < EE; ++e){
      counts[e] = lc[e]; offs[e] = run; curs[e] = run; run += lc[e];
    }
    offs[EE] = run;
  }
}

__global__ __launch_bounds__(256) void moe_scatter(const int* __restrict__ eids,
    const float* __restrict__ wts, int* __restrict__ curs,
    int* __restrict__ rowmap, float* __restrict__ wgtm)
{
  int i = blockIdx.x * 256 + threadIdx.x;
  int e = eids[i];
  int pos = atomicAdd(&curs[e], 1);
  rowmap[pos] = i >> 1;
  wgtm[pos] = wts[i];
}

__global__ __launch_bounds__(256) void add2(const float* __restrict__ a,
    const float* __restrict__ b, float* __restrict__ o, int n)
{
  int i = blockIdx.x * 256 + threadIdx.x;
  if (i < n) o[i] = a[i] + b[i];
}

// ---------------- MoE expert GEMM1: H = gelu(gather(xn2b) @ W1t^T + b1) --------------
__global__ __launch_bounds__(256) void gemm_moe1(
    const u16* __restrict__ Xb, const u16* __restrict__ W1t, const float* __restrict__ b1,
    u16* __restrict__ H, const int* __restrict__ counts, const int* __restrict__ offs,
    const int* __restrict__ rowmap)
{
  int e = blockIdx.z;
  int cnt = counts[e];
  int m0 = blockIdx.y * 128;
  if (m0 >= cnt) return;
  int off = offs[e];
  int n0 = blockIdx.x * 128;
  const u16* Bt = W1t + (size_t)e * DFFN * CC;
  __shared__ u16 As[128 * 32];
  __shared__ u16 Bs[128 * 32];
  int tid = threadIdx.x;
  int lane = tid & 63, wave = tid >> 6;
  int wm = wave & 1, wn = wave >> 1;
  int ra = tid >> 2, ka = (tid & 3) * 8;
  int r0 = m0 + ra, r1i = m0 + ra + 64;
  int rr0 = (r0  < cnt) ? r0  : cnt - 1;   // clamp: rows >= cnt discarded in epilogue
  int rr1 = (r1i < cnt) ? r1i : cnt - 1;
  const u16* pa0 = Xb + (size_t)rowmap[off + rr0] * CC + ka;
  const u16* pa1 = Xb + (size_t)rowmap[off + rr1] * CC + ka;
  const u16* pb0 = Bt + (size_t)(n0 + ra)      * CC + ka;
  const u16* pb1 = Bt + (size_t)(n0 + ra + 64) * CC + ka;
  u16* lA0 = As + wave*512;        u16* lA1 = As + 2048 + wave*512;
  u16* lB0 = Bs + wave*512;        u16* lB1 = Bs + 2048 + wave*512;
  floatx4 acc[4][4] = {};
  int el = lane & 15, eq = lane >> 4;
  for (int k0 = 0; k0 < CC; k0 += 32){
    __syncthreads();
    gload_lds16(pa0 + k0, lA0);
    gload_lds16(pa1 + k0, lA1);
    gload_lds16(pb0 + k0, lB0);
    gload_lds16(pb1 + k0, lB1);
    __syncthreads();
    short8 fa[4], fb[4];
    #pragma unroll
    for (int t = 0; t < 4; ++t)
      fa[t] = *(const short8*)&As[(size_t)(wm*64 + t*16 + el) * 32 + eq*8];
    #pragma unroll
    for (int t = 0; t < 4; ++t)
      fb[t] = *(const short8*)&Bs[(size_t)(wn*64 + t*16 + el) * 32 + eq*8];
    #pragma unroll
    for (int mt = 0; mt < 4; ++mt)
      #pragma unroll
      for (int nt = 0; nt < 4; ++nt)
        acc[mt][nt] = __builtin_amdgcn_mfma_f32_16x16x32_bf16(fa[mt], fb[nt], acc[mt][nt], 0, 0, 0);
  }
  #pragma unroll
  for (int mt = 0; mt < 4; ++mt){
    #pragma unroll
    for (int nt = 0; nt < 4; ++nt){
      int col = n0 + wn*64 + nt*16 + el;
      float bv = b1[(size_t)e * DFFN + col];
      #pragma unroll
      for (int r = 0; r < 4; ++r){
        int row = m0 + wm*64 + mt*16 + eq*4 + r;
        if (row < cnt)
          H[(size_t)(off + row) * DFFN + col] = f2bf(gelu_exact(acc[mt][nt][r] + bv));
      }
    }
  }
}

// ---------------- MoE expert GEMM2 (K-split x2): out[tok] += w * (H @ W2t^T + b2) ----
#define KSPL 2
__global__ __launch_bounds__(256) void gemm_moe2(
    const u16* __restrict__ H, const u16* __restrict__ W2t, const float* __restrict__ b2,
    float* __restrict__ Out, const int* __restrict__ counts, const int* __restrict__ offs,
    const int* __restrict__ rowmap, const float* __restrict__ wgtm)
{
  int e = blockIdx.z;
  int cnt = counts[e];
  int m0 = blockIdx.y * 128;
  if (m0 >= cnt) return;
  int off = offs[e];
  int bx = blockIdx.x;
  int n0 = (bx % 6) * 128;
  int ksp = bx / 6;
  const u16* Bt = W2t + (size_t)e * CC * DFFN;
  __shared__ u16 As[128 * 32];
  __shared__ u16 Bs[128 * 32];
  int tid = threadIdx.x;
  int lane = tid & 63, wave = tid >> 6;
  int wm = wave & 1, wn = wave >> 1;
  int ra = tid >> 2, ka = (tid & 3) * 8;
  int r0 = m0 + ra, r1i = m0 + ra + 64;
  int rr0 = (r0  < cnt) ? r0  : cnt - 1;
  int rr1 = (r1i < cnt) ? r1i : cnt - 1;
  const u16* pa0 = H + (size_t)(off + rr0) * DFFN + ka;
  const u16* pa1 = H + (size_t)(off + rr1) * DFFN + ka;
  const u16* pb0 = Bt + (size_t)(n0 + ra)      * DFFN + ka;
  const u16* pb1 = Bt + (size_t)(n0 + ra + 64) * DFFN + ka;
  u16* lA0 = As + wave*512;        u16* lA1 = As + 2048 + wave*512;
  u16* lB0 = Bs + wave*512;        u16* lB1 = Bs + 2048 + wave*512;
  floatx4 acc[4][4] = {};
  int el = lane & 15, eq = lane >> 4;
  int kbeg = ksp * (DFFN / KSPL), kend = kbeg + DFFN / KSPL;
  for (int k0 = kbeg; k0 < kend; k0 += 32){
    __syncthreads();
    gload_lds16(pa0 + k0, lA0);
    gload_lds16(pa1 + k0, lA1);
    gload_lds16(pb0 + k0, lB0);
    gload_lds16(pb1 + k0, lB1);
    __syncthreads();
    short8 fa[4], fb[4];
    #pragma unroll
    for (int t = 0; t < 4; ++t)
      fa[t] = *(const short8*)&As[(size_t)(wm*64 + t*16 + el) * 32 + eq*8];
    #pragma unroll
    for (int t = 0; t < 4; ++t)
      fb[t] = *(const short8*)&Bs[(size_t)(wn*64 + t*16 + el) * 32 + eq*8];
    #pragma unroll
    for (int mt = 0; mt < 4; ++mt)
      #pragma unroll
      for (int nt = 0; nt < 4; ++nt)
        acc[mt][nt] = __builtin_amdgcn_mfma_f32_16x16x32_bf16(fa[mt], fb[nt], acc[mt][nt], 0, 0, 0);
  }
  #pragma unroll
  for (int mt = 0; mt < 4; ++mt){
    #pragma unroll
    for (int nt = 0; nt < 4; ++nt){
      int col = n0 + wn*64 + nt*16 + el;
      float bv = (ksp == 0) ? b2[(size_t)e * CC + col] : 0.f;
      #pragma unroll
      for (int r = 0; r < 4; ++r){
        int row = m0 + wm*64 + mt*16 + eq*4 + r;
        if (row < cnt){
          int slot = off + row;
          int tok = rowmap[slot];
          float wv = wgtm[slot];
          atomicAdd(&Out[(size_t)tok * CC + col], wv * (acc[mt][nt][r] + bv));
        }
      }
    }
  }
}

// =====================================================================================
extern "C" void kernel_launch(void* const* d_in, const int* in_sizes, int n_in,
                              void* d_out, int out_size, void* d_ws, size_t ws_size,
                              hipStream_t stream)
{
  const float* x     = (const float*)d_in[0];
  const float* ln1w  = (const float*)d_in[1];
  const float* ln1b  = (const float*)d_in[2];
  const float* Wattn = (const float*)d_in[3];
  const float* battn = (const float*)d_in[4];
  const float* Wproj = (const float*)d_in[5];
  const float* bproj = (const float*)d_in[6];
  const float* ln2w  = (const float*)d_in[7];
  const float* ln2b  = (const float*)d_in[8];
  const float* Wrout = (const float*)d_in[9];
  const float* W1    = (const float*)d_in[10];
  const float* b1    = (const float*)d_in[11];
  const float* W2    = (const float*)d_in[12];
  const float* b2    = (const float*)d_in[13];
  float* out = (float*)d_out;

  char* w = (char*)d_ws;
  auto alloc = [&](size_t bytes)->char* {
    char* p = w; w += (bytes + 255) & ~(size_t)255; return p;
  };
  u16* watp  = (u16*)alloc((size_t)C3 * LDA2 * 2);      //  7.1 MB  fp16 2-split [N][1536]
  u16* wptp  = (u16*)alloc((size_t)CC * LDA2 * 2);      //  2.4 MB
  u16* w1t   = (u16*)alloc((size_t)EE * DFFN * CC * 2); // 75.5 MB  bf16
  u16* w2t   = (u16*)alloc((size_t)EE * CC * DFFN * 2); // 75.5 MB
  u16* xH    = (u16*)alloc((size_t)NTOK * LDA2 * 2);    // 12.6 MB  LN1 out, fp16 2-split
  float* qkv = (float*)alloc((size_t)NTOK * C3 * 4);    // 37.7 MB
  u16* yH    = (u16*)alloc((size_t)NTOK * LDA2 * 2);    // 12.6 MB  attn out, fp16 2-split
  u16* Hbuf  = (u16*)alloc((size_t)NSLOT * DFFN * 2);   // 50.3 MB
  float* x2    = (float*)alloc((size_t)NTOK * CC * 4);
  float* xn2   = (float*)alloc((size_t)NTOK * CC * 4);
  u16*   xn2b  = (u16*)alloc((size_t)NTOK * CC * 2);
  int*   eids  = (int*)alloc(NSLOT * 4);
  float* wts   = (float*)alloc(NSLOT * 4);
  int* counts  = (int*)alloc(256);
  int* offs    = (int*)alloc(256);
  int* curs    = (int*)alloc(256);
  int* rowmap  = (int*)alloc(NSLOT * 4);
  float* wgtm  = (float*)alloc(NSLOT * 4);

  // 1) weight conversion
  hipLaunchKernelGGL((transpose_split<1>), dim3(C3/32, CC/32, 1), dim3(256), 0, stream,
                     Wattn, watp, CC, C3);
  hipLaunchKernelGGL((transpose_split<1>), dim3(CC/32, CC/32, 1), dim3(256), 0, stream,
                     Wproj, wptp, CC, CC);
  hipLaunchKernelGGL((transpose_split<0>), dim3(DFFN/32, CC/32, EE), dim3(256), 0, stream,
                     W1, w1t, CC, DFFN);
  hipLaunchKernelGGL((transpose_split<0>), dim3(CC/32, DFFN/32, EE), dim3(256), 0, stream,
                     W2, w2t, DFFN, CC);
  // 2) LN1 -> fp16 2-split xH
  hipLaunchKernelGGL((ln_kernel<1>), dim3(NTOK), dim3(256), 0, stream,
                     x, ln1w, ln1b, (float*)nullptr, xH);
  // 3) qkv = xn @ W_attn + b_attn (single K=2304 fp16 3-term pass, async staging)
  hipLaunchKernelGGL(gemm_dense, dim3(C3/128, NTOK/128), dim3(256), 0, stream,
                     xH, watp, qkv, battn, (const float*)nullptr, C3);
  // 4) MFMA flash attention (Q-tile 64, 2 blocks/CU) -> yH (fp16 2-split)
  hipLaunchKernelGGL(flash_mfma, dim3(16, BB*HH), dim3(256), 0, stream, qkv, yH);
  // 5) x2 = x + y @ W_proj + b_proj (residual folded into epilogue)
  hipLaunchKernelGGL(gemm_dense, dim3(CC/128, NTOK/128), dim3(256), 0, stream,
                     yH, wptp, x2, bproj, x, CC);
  // 6) LN2 -> xn2 fp32 (router) + bf16 (MoE input)
  hipLaunchKernelGGL((ln_kernel<0>), dim3(NTOK), dim3(256), 0, stream,
                     x2, ln2w, ln2b, xn2, xn2b);
  // 7) router + expert gather lists
  hipLaunchKernelGGL(router_kernel, dim3(NTOK/4), dim3(256), 0, stream, xn2, Wrout, eids, wts);
  hipLaunchKernelGGL(moe_count, dim3(1), dim3(256), 0, stream, eids, counts, offs, curs);
  hipLaunchKernelGGL(moe_scatter, dim3(NSLOT/256), dim3(256), 0, stream, eids, wts, curs, rowmap, wgtm);
  // 8) out = x2 + xn2
  hipLaunchKernelGGL(add2, dim3(NTOK*CC/256), dim3(256), 0, stream, x2, xn2, out, NTOK*CC);
  // 9) MoE expert FFN
  hipLaunchKernelGGL(gemm_moe1, dim3(DFFN/128, 32, EE), dim3(256), 0, stream,
                     xn2b, w1t, b1, Hbuf, counts, offs, rowmap);
  hipLaunchKernelGGL(gemm_moe2, dim3(6*KSPL, 32, EE), dim3(256), 0, stream,
                     Hbuf, w2t, b2, out, counts, offs, rowmap, wgtm);
}